// Round 8
// baseline (1947.632 us; speedup 1.0000x reference)
//
#include <hip/hip_runtime.h>
#include <cstdint>

typedef unsigned short u16;
typedef __attribute__((ext_vector_type(8))) short s16x8;
typedef __attribute__((ext_vector_type(4))) float f32x4;

#define NTOK 4096
#define DH   64
#define DM   1024
#define NH   16

static __device__ __forceinline__ float b2f(u16 u){ return __uint_as_float(((unsigned)u)<<16); }
static __device__ __forceinline__ u16 f2b(float f){
  unsigned u = __float_as_uint(f);
  return (u16)((u + 0x7FFFu + ((u>>16)&1u)) >> 16);   // RNE
}

static __device__ __forceinline__ void gload_lds16(const void* g, void* l) {
  __builtin_amdgcn_global_load_lds(
      (const __attribute__((address_space(1))) unsigned*)(uintptr_t)g,
      (__attribute__((address_space(3))) unsigned*)(uintptr_t)l, 16, 0, 0);
}

static __device__ __forceinline__ s16x8 ld8(const u16* p){ return *(const s16x8*)(const void*)p; }

// ---------------- fused: hs -> bf16 Xb  AND  landmark means Xl (fp32) ----------------
__global__ __launch_bounds__(256) void k_cvt_xl(const float* __restrict__ hs, u16* __restrict__ Xb,
                                                float* __restrict__ Xl) {
  const int grp = blockIdx.x;                 // b*64 + lm (64-token group)
  const int d = blockIdx.y*256 + threadIdx.x;
  const float* p = hs + (long)grp*64*DM + d;
  u16* xo = Xb + (long)grp*64*DM + d;
  float s = 0.f;
  #pragma unroll 8
  for (int i = 0; i < 64; ++i) {
    const float v = p[(long)i*DM];
    s += v;
    xo[(long)i*DM] = f2b(v);
  }
  Xl[(long)grp*DM + d] = s * (1.0f/64.0f);
}

// ---------------- convert+transpose: f32 [R][C] -> bf16 [C][R] ----------------
__global__ __launch_bounds__(256) void k_cvt_t(const float* __restrict__ in, u16* __restrict__ out, int R, int C) {
  __shared__ float tile[64][65];
  const int tc = blockIdx.x, tr = blockIdx.y;
  const int t = threadIdx.x, cx = t & 63, ry = t >> 6;
  #pragma unroll
  for (int p = 0; p < 16; ++p) {
    const int row = p*4 + ry;
    tile[row][cx] = in[(long)(tr*64 + row)*C + tc*64 + cx];
  }
  __syncthreads();
  #pragma unroll
  for (int p = 0; p < 16; ++p) {
    const int orow = p*4 + ry;
    out[(long)(tc*64 + orow)*R + tr*64 + cx] = f2b(tile[cx][orow]);
  }
}

// ---------------- fp32 projection, K-split: psum[z][row][col] partials ----------------
__global__ __launch_bounds__(256) void k_lproj2(const float* __restrict__ Xl, const float* __restrict__ Wqkv,
                                                float* __restrict__ psum) {
  __shared__ __align__(16) float Xs[32][68];
  const int t = threadIdx.x;
  const int wcol = blockIdx.x*256 + t;    // 0..2047
  const int r0 = blockIdx.y*32;
  const int kbase = blockIdx.z*128;
  float acc[32];
  #pragma unroll
  for (int r = 0; r < 32; ++r) acc[r] = 0.f;
  for (int k0 = kbase; k0 < kbase + 128; k0 += 64) {
    __syncthreads();
    for (int idx = t; idx < 2048; idx += 256)
      Xs[idx>>6][idx&63] = Xl[(long)(r0 + (idx>>6))*DM + k0 + (idx&63)];
    __syncthreads();
    for (int kk = 0; kk < 64; kk += 4) {
      f32x4 wv;
      #pragma unroll
      for (int j = 0; j < 4; ++j) wv[j] = Wqkv[(long)(k0+kk+j)*3072 + wcol];
      #pragma unroll
      for (int r = 0; r < 32; ++r) {
        const f32x4 xv = *(const f32x4*)&Xs[r][kk];
        acc[r] += xv[0]*wv[0] + xv[1]*wv[1] + xv[2]*wv[2] + xv[3]*wv[3];
      }
    }
  }
  float* po = psum + ((long)blockIdx.z*256 + r0)*2048 + wcol;
  #pragma unroll
  for (int r = 0; r < 32; ++r) po[(long)r*2048] = acc[r];
}

// ---------------- reduce K-slices + bias + scale -> qlf/klf/qlb/klb ----------------
__global__ __launch_bounds__(256) void k_lreduce(const float* __restrict__ psum, const float* __restrict__ bqkv,
                                                 float* __restrict__ qlf, float* __restrict__ klf,
                                                 u16* __restrict__ qlb, u16* __restrict__ klb) {
  const long idx = (long)blockIdx.x*256 + threadIdx.x;   // 0..524287
  const int row = (int)(idx >> 11), col = (int)(idx & 2047);
  float s = 0.f;
  #pragma unroll
  for (int z = 0; z < 8; ++z) s += psum[((long)z*256 + row)*2048 + col];
  const int isq = (col < 1024) ? 1 : 0;
  float val = s + bqkv[col];
  if (isq) val *= 0.125f;
  const int b = row >> 6, lm = row & 63;
  const int c2 = col & 1023, h = c2 >> 6, dh = c2 & 63;
  const long o = (((long)b*NH + h)*64 + lm)*64 + dh;
  if (isq) { qlf[o] = val; qlb[o] = f2b(val); }
  else     { klf[o] = val; klb[o] = f2b(val); }
}

// ---------------- GEMM 256x256, BK=32, 8 waves, depth-2 LDS ring (64KB -> 2 blocks/CU) ----------------
// r8: ring depth 4->2 to double occupancy; cross-block overlap covers the per-tile drain.
// Ledger: stage(kt+1)->buf[(kt+1)&1] at top of kt (its reads finished at barrier kt-1);
//   lgkmcnt(0) drains buf[kt&1] reads, vmcnt(0) confirms stage(kt+1) landed, then barrier;
//   nf/nb reads of buf[(kt+1)&1] happen after that barrier. Race-free.
// LDS swizzle (r5-verified): source chunk ^ (row>>1)&3, read offset g ^ (c>>1)&3.
template<int EPI>
__global__ __launch_bounds__(512, 4) void k_gemm256(
    const u16* __restrict__ A, const u16* __restrict__ Bt, const float* __restrict__ bias,
    int N, float* __restrict__ outF, u16* __restrict__ outQ, u16* __restrict__ outK, u16* __restrict__ outV)
{
  __shared__ __align__(16) u16 lds[2*16384];
  const int K = 1024;
  const int t = threadIdx.x;
  const int lane = t & 63;
  const int wid = t >> 6;
  const int c = lane & 15, g = lane >> 4;
  const int wm = wid >> 2, wn = wid & 3;
  // XCD-aware remap (kept from r7; bijective, neutral-to-positive)
  const int fid = blockIdx.y*64 + blockIdx.x;
  const int nbx = ((fid & 7) << 3) | ((fid >> 3) & 7);
  const int nby = fid >> 6;
  const long arow0 = (long)nbx * 256;
  const long brow0 = (long)nby * 256;
  char* ldsb = (char*)lds;

  const int srow = t >> 2;
  const int schunk = (t & 3) ^ ((srow >> 1) & 3);
  const u16* gA0 = A  + (arow0 + srow)*K       + schunk*8;
  const u16* gA1 = A  + (arow0 + 128 + srow)*K + schunk*8;
  const u16* gB0 = Bt + (brow0 + srow)*K       + schunk*8;
  const u16* gB1 = Bt + (brow0 + 128 + srow)*K + schunk*8;
  const int dstoff = t*16;

#define STAGE_A(kt) { char* bse = ldsb + ((kt)&1)*32768; \
    gload_lds16(gA0 + (kt)*32, bse + dstoff); \
    gload_lds16(gA1 + (kt)*32, bse + 8192 + dstoff); }
#define STAGE_B(kt) { char* bse = ldsb + ((kt)&1)*32768 + 16384; \
    gload_lds16(gB0 + (kt)*32, bse + dstoff); \
    gload_lds16(gB1 + (kt)*32, bse + 8192 + dstoff); }

  const int gs = g ^ ((c >> 1) & 3);
  int aoff[2][4], boff[4];
  #pragma unroll
  for (int mi = 0; mi < 4; ++mi) {
    aoff[0][mi] = (0*128 + wm*64 + mi*16 + c)*64 + gs*16;
    aoff[1][mi] = (1*128 + wm*64 + mi*16 + c)*64 + gs*16;
    boff[mi]    = 16384 + (wn*64 + mi*16 + c)*64 + gs*16;
  }

  f32x4 acc0[4][4] = {};
  f32x4 acc1[4][4] = {};

  // prologue: stage tile 0, wait, read first af/bfr
  STAGE_A(0); STAGE_B(0);
  asm volatile("s_waitcnt vmcnt(0)" ::: "memory");
  __builtin_amdgcn_s_barrier();

  s16x8 af[4], bfr[4], af2[4];
  #pragma unroll
  for (int mi = 0; mi < 4; ++mi) af[mi]  = *(const s16x8*)(ldsb + aoff[0][mi]);
  #pragma unroll
  for (int ni = 0; ni < 4; ++ni) bfr[ni] = *(const s16x8*)(ldsb + boff[ni]);

  for (int kt = 0; kt < 32; ++kt) {
    char* buf  = ldsb + (kt&1)*32768;
    char* bufn = ldsb + ((kt+1)&1)*32768;
    if (kt + 1 < 32) { STAGE_A(kt+1) STAGE_B(kt+1) }
    // drain af/bfr reads (issued last iter), then issue af2 under acc0's MFMAs
    asm volatile("s_waitcnt lgkmcnt(0)" ::: "memory");
    __builtin_amdgcn_sched_barrier(0);
    #pragma unroll
    for (int mi = 0; mi < 4; ++mi) af2[mi] = *(const s16x8*)(buf + aoff[1][mi]);
    __builtin_amdgcn_sched_barrier(0);
    __builtin_amdgcn_s_setprio(1);
    #pragma unroll
    for (int mi = 0; mi < 4; ++mi)
      #pragma unroll
      for (int ni = 0; ni < 4; ++ni)
        acc0[mi][ni] = __builtin_amdgcn_mfma_f32_16x16x32_bf16(af[mi], bfr[ni], acc0[mi][ni], 0, 0, 0);
    __builtin_amdgcn_s_setprio(0);
    // drain af2 reads; ensure stage(kt+1) landed; barrier; then prefetch next-tile frags
    asm volatile("s_waitcnt lgkmcnt(0)" ::: "memory");
    __builtin_amdgcn_sched_barrier(0);
    if (kt + 1 < 32) { asm volatile("s_waitcnt vmcnt(0)" ::: "memory"); }
    __builtin_amdgcn_s_barrier();
    s16x8 nf[4], nb[4];
    if (kt < 31) {
      #pragma unroll
      for (int mi = 0; mi < 4; ++mi) nf[mi] = *(const s16x8*)(bufn + aoff[0][mi]);
      #pragma unroll
      for (int ni = 0; ni < 4; ++ni) nb[ni] = *(const s16x8*)(bufn + boff[ni]);
    }
    __builtin_amdgcn_sched_barrier(0);
    __builtin_amdgcn_s_setprio(1);
    #pragma unroll
    for (int mi = 0; mi < 4; ++mi)
      #pragma unroll
      for (int ni = 0; ni < 4; ++ni)
        acc1[mi][ni] = __builtin_amdgcn_mfma_f32_16x16x32_bf16(af2[mi], bfr[ni], acc1[mi][ni], 0, 0, 0);
    __builtin_amdgcn_s_setprio(0);
    if (kt < 31) {
      #pragma unroll
      for (int mi = 0; mi < 4; ++mi) { af[mi] = nf[mi]; bfr[mi] = nb[mi]; }
    }
  }
#undef STAGE_A
#undef STAGE_B

  if (EPI == 0) {
    const int tensor = (int)(brow0 >> 10);
    u16* dst = (tensor == 0) ? outQ : (tensor == 1) ? outK : outV;
    const float mul = (tensor == 0) ? 0.125f : 1.0f;
    #pragma unroll
    for (int ph = 0; ph < 2; ++ph)
      #pragma unroll
      for (int mi = 0; mi < 4; ++mi) {
        const int rowb = ph*128 + wm*64 + mi*16 + g*4;
        #pragma unroll
        for (int ni = 0; ni < 4; ++ni) {
          const long gcol = brow0 + wn*64 + ni*16 + c;
          const int c2 = (int)(gcol & 1023);
          const int head = c2 >> 6, dh = c2 & 63;
          const float bv = bias[gcol];
          const f32x4 a = ph ? acc1[mi][ni] : acc0[mi][ni];
          #pragma unroll
          for (int r = 0; r < 4; ++r) {
            const long grow = arow0 + rowb + r;
            const int b = (int)(grow >> 12), tok = (int)(grow & 4095);
            dst[(((long)b*NH + head)*NTOK + tok)*DH + dh] = f2b((a[r] + bv)*mul);
          }
        }
      }
  } else {
    #pragma unroll
    for (int ph = 0; ph < 2; ++ph)
      #pragma unroll
      for (int mi = 0; mi < 4; ++mi) {
        const int rowb = ph*128 + wm*64 + mi*16 + g*4;
        #pragma unroll
        for (int ni = 0; ni < 4; ++ni) {
          const long gcol = brow0 + wn*64 + ni*16 + c;
          const float bv = bias[gcol];
          const f32x4 a = ph ? acc1[mi][ni] : acc0[mi][ni];
          #pragma unroll
          for (int r = 0; r < 4; ++r) {
            const long grow = arow0 + rowb + r;
            outF[grow*N + gcol] = a[r] + bv;
          }
        }
      }
  }
}

// ---------------- v transpose: [bh][tok][dh] -> [bh][dh][tok] ----------------
__global__ __launch_bounds__(256) void k_vtrans(const u16* __restrict__ v, u16* __restrict__ vt) {
  __shared__ u16 tile[64][65];
  const int bh = blockIdx.x >> 6, tt = blockIdx.x & 63;
  const int t = threadIdx.x, cx = t & 63, ry = t >> 6;
  const u16* vp = v + ((long)bh*NTOK + tt*64)*DH;
  #pragma unroll
  for (int p = 0; p < 16; ++p) { const int row = p*4 + ry; tile[row][cx] = vp[row*DH + cx]; }
  __syncthreads();
  u16* op = vt + (long)bh*DH*NTOK + tt*64;
  #pragma unroll
  for (int p = 0; p < 16; ++p) { const int orow = p*4 + ry; op[(long)orow*NTOK + cx] = tile[cx][orow]; }
}

// ---------------- fp32 LDS 64x64 matmul helpers, 512 threads (8 cols/thread) ----------------
#define PST 68
static __device__ __forceinline__ void mm_nn8(const float* A, const float* B, float* C, int t) {
  const int lane = t & 63, j0 = (t >> 6) << 3;
  float acc[8];
  #pragma unroll
  for (int j = 0; j < 8; ++j) acc[j] = 0.f;
  for (int k = 0; k < 64; k += 4) {
    const f32x4 a4 = *(const f32x4*)&A[lane*PST + k];
    #pragma unroll
    for (int dk = 0; dk < 4; ++dk) {
      const float a = a4[dk];
      const float* br = &B[(k + dk)*PST + j0];
      const f32x4 b0 = *(const f32x4*)(br);
      const f32x4 b1 = *(const f32x4*)(br + 4);
      #pragma unroll
      for (int qq = 0; qq < 4; ++qq) { acc[qq] += a*b0[qq]; acc[4+qq] += a*b1[qq]; }
    }
  }
  #pragma unroll
  for (int j = 0; j < 8; ++j) C[lane*PST + j0 + j] = acc[j];
}
static __device__ __forceinline__ void mm_nt8(const float* A, const float* B, float* C, int t) {
  const int lane = t & 63, j0 = (t >> 6) << 3;
  float acc[8];
  #pragma unroll
  for (int j = 0; j < 8; ++j) acc[j] = 0.f;
  for (int k = 0; k < 64; k += 4) {
    const f32x4 a4 = *(const f32x4*)&A[lane*PST + k];
    #pragma unroll
    for (int jj = 0; jj < 8; ++jj) {
      const f32x4 b4 = *(const f32x4*)&B[(j0 + jj)*PST + k];
      acc[jj] += a4[0]*b4[0] + a4[1]*b4[1] + a4[2]*b4[2] + a4[3]*b4[3];
    }
  }
  #pragma unroll
  for (int j = 0; j < 8; ++j) C[lane*PST + j0 + j] = acc[j];
}

// ---------------- sim2 + softmax + Newton-Schulz pinv (all fp32, 512 thr) ----------------
__global__ __launch_bounds__(512) void k_pinv(const float* __restrict__ qlf, const float* __restrict__ klf,
                                              float* __restrict__ a2inv) {
  __shared__ __align__(16) float Xb[64*PST];
  __shared__ __align__(16) float Vb[64*PST];
  __shared__ __align__(16) float T1[64*PST];
  __shared__ __align__(16) float T2[64*PST];
  __shared__ __align__(16) float T3[64*PST];
  const int bh = blockIdx.x, t = threadIdx.x;
  const float* ql = qlf + (long)bh*4096;
  const float* kl = klf + (long)bh*4096;
  for (int i = t; i < 4096; i += 512) { T1[(i>>6)*PST + (i&63)] = ql[i]; T2[(i>>6)*PST + (i&63)] = kl[i]; }
  __syncthreads();
  mm_nt8(T1, T2, Xb, t);          // sim2 = q_l @ k_l^T
  __syncthreads();
  if (t < 64) {                   // row softmax (precise exp on the chaotic path)
    float mx = -1e30f;
    for (int j = 0; j < 64; ++j) mx = fmaxf(mx, Xb[t*PST + j]);
    float s = 0.f;
    for (int j = 0; j < 64; ++j) { const float e = expf(Xb[t*PST + j] - mx); Xb[t*PST + j] = e; s += e; }
    const float inv = 1.0f/s;
    for (int j = 0; j < 64; ++j) Xb[t*PST + j] *= inv;
  }
  __syncthreads();
  for (int i = t; i < 4096; i += 512) { const int r = i>>6, cc = i&63; Vb[r*PST+cc] = Xb[r*PST+cc]; }
  __syncthreads();
  for (int it = 0; it < 6; ++it) {
    mm_nn8(Xb, Vb, T1, t);  __syncthreads();                 // KV
    for (int i = t; i < 4096; i += 512) { const int r=i>>6, cc=i&63; T2[r*PST+cc] = (r==cc?7.0f:0.0f) - T1[r*PST+cc]; }
    __syncthreads();
    mm_nn8(T1, T2, T3, t);  __syncthreads();                 // KV@(7I-KV)
    for (int i = t; i < 4096; i += 512) { const int r=i>>6, cc=i&63; T2[r*PST+cc] = (r==cc?15.0f:0.0f) - T3[r*PST+cc]; }
    __syncthreads();
    mm_nn8(T1, T2, T3, t);  __syncthreads();                 // KV@(15I-...)
    for (int i = t; i < 4096; i += 512) { const int r=i>>6, cc=i&63; T2[r*PST+cc] = (r==cc?13.0f:0.0f) - T3[r*PST+cc]; }
    __syncthreads();
    mm_nn8(Vb, T2, T3, t);  __syncthreads();                 // V@(13I-...)
    for (int i = t; i < 4096; i += 512) { const int r=i>>6, cc=i&63; Vb[r*PST+cc] = 0.25f*T3[r*PST+cc]; }
    __syncthreads();
  }
  for (int i = t; i < 4096; i += 512) a2inv[(long)bh*4096 + i] = Vb[(i>>6)*PST + (i&63)];
}

// ---------------- attn3 @ v partials: 4 blocks per (b,h), 1024 tokens each ----------------
__global__ __launch_bounds__(256) void k_attn3v_p(const u16* __restrict__ qlb, const u16* __restrict__ kk,
                                                  const u16* __restrict__ vt,
                                                  float* __restrict__ zp, float* __restrict__ sp) {
  __shared__ __align__(16) float Zl[4][64][64];
  __shared__ float Sl[4][64];
  __shared__ __align__(16) u16 Pl[4][64][40];   // rows padded to 80B (32 cols used)
  const int bh = blockIdx.x >> 2, qt = blockIdx.x & 3;
  const int t = threadIdx.x, w = t >> 6, lane = t & 63;
  const int c = lane & 15, g = lane >> 4;

  s16x8 aq[4][2];
  const u16* qlp = qlb + (long)bh*4096;
  #pragma unroll
  for (int mi = 0; mi < 4; ++mi)
    #pragma unroll
    for (int ks = 0; ks < 2; ++ks)
      aq[mi][ks] = ld8(qlp + (mi*16 + c)*64 + ks*32 + g*8);

  f32x4 zacc[4][4] = {};
  float sl[4][4] = {};
  const u16* kp = kk + (long)bh*NTOK*DH;
  const u16* vp = vt + (long)bh*DH*NTOK;
  char* pbase = (char*)&Pl[w][0][0];
  const int tok00 = qt*1024 + w*256;

  for (int it = 0; it < 8; ++it) {
    const int t0 = tok00 + it*32;
    f32x4 sacc[4][2] = {};
    s16x8 kb[2][2];
    #pragma unroll
    for (int cg = 0; cg < 2; ++cg)
      #pragma unroll
      for (int ks = 0; ks < 2; ++ks)
        kb[cg][ks] = ld8(kp + (long)(t0 + cg*16 + c)*64 + ks*32 + g*8);
    #pragma unroll
    for (int cg = 0; cg < 2; ++cg)
      #pragma unroll
      for (int ks = 0; ks < 2; ++ks)
        #pragma unroll
        for (int mi = 0; mi < 4; ++mi)
          sacc[mi][cg] = __builtin_amdgcn_mfma_f32_16x16x32_bf16(aq[mi][ks], kb[cg][ks], sacc[mi][cg], 0, 0, 0);
    #pragma unroll
    for (int mi = 0; mi < 4; ++mi)
      #pragma unroll
      for (int r = 0; r < 4; ++r) {
        const int row = mi*16 + g*4 + r;
        const float p0 = __expf(sacc[mi][0][r]);
        const float p1 = __expf(sacc[mi][1][r]);
        sl[mi][r] += p0 + p1;
        char* base = pbase + row*80;
        *(u16*)(base + c*2)      = f2b(p0);
        *(u16*)(base + 32 + c*2) = f2b(p1);
      }
    s16x8 pa[4];
    #pragma unroll
    for (int mi = 0; mi < 4; ++mi) pa[mi] = *(const s16x8*)(pbase + (mi*16 + c)*80 + g*16);
    #pragma unroll
    for (int ni = 0; ni < 4; ++ni) {
      const s16x8 vb = ld8(vp + (long)(ni*16 + c)*NTOK + t0 + g*8);
      #pragma unroll
      for (int mi = 0; mi < 4; ++mi)
        zacc[mi][ni] = __builtin_amdgcn_mfma_f32_16x16x32_bf16(pa[mi], vb, zacc[mi][ni], 0, 0, 0);
    }
  }
  #pragma unroll
  for (int mi = 0; mi < 4; ++mi)
    #pragma unroll
    for (int r = 0; r < 4; ++r) {
      float s = sl[mi][r];
      s += __shfl_xor(s, 1); s += __shfl_xor(s, 2); s += __shfl_xor(s, 4); s += __shfl_xor(s, 8);
      sl[mi][r] = s;
    }
  #pragma unroll
  for (int mi = 0; mi < 4; ++mi)
    #pragma unroll
    for (int ni = 0; ni < 4; ++ni)
      #pragma unroll
      for (int r = 0; r < 4; ++r)
        Zl[w][mi*16 + g*4 + r][ni*16 + c] = zacc[mi][ni][r];
  if (c == 0)
    #pragma unroll
    for (int mi = 0; mi < 4; ++mi)
      #pragma unroll
      for (int r = 0; r < 4; ++r)
        Sl[w][mi*16 + g*4 + r] = sl[mi][r];
  __syncthreads();
  float* zpp = zp + (long)blockIdx.x*4096;
  for (int i = t; i < 4096; i += 256) {
    const int row = i >> 6, dh = i & 63;
    zpp[i] = Zl[0][row][dh] + Zl[1][row][dh] + Zl[2][row][dh] + Zl[3][row][dh];
  }
  if (t < 64) sp[(long)blockIdx.x*64 + t] = Sl[0][t] + Sl[1][t] + Sl[2][t] + Sl[3][t];
}

// ---------------- fused: z-reduce + W2^T = (attn2inv @ z)^T  (bf16 [dh][lm], 512 thr) ----------------
__global__ __launch_bounds__(512) void k_w2(const float* __restrict__ a2inv,
                                            const float* __restrict__ zp, const float* __restrict__ sp,
                                            u16* __restrict__ w2t) {
  __shared__ __align__(16) float Ai[64*PST];
  __shared__ __align__(16) float Zi[64*PST];
  __shared__ __align__(16) float Ci[64*PST];
  __shared__ float Ss[64];
  const int bh = blockIdx.x, t = threadIdx.x;
  if (t < 64) {
    float ss = 0.f;
    #pragma unroll
    for (int qt = 0; qt < 4; ++qt) ss += sp[(long)(bh*4 + qt)*64 + t];
    Ss[t] = 1.0f / ss;
  }
  for (int i = t; i < 4096; i += 512)
    Ai[(i>>6)*PST + (i&63)] = a2inv[(long)bh*4096 + i];
  __syncthreads();
  for (int i = t; i < 4096; i += 512) {
    float zs = 0.f;
    #pragma unroll
    for (int qt = 0; qt < 4; ++qt) zs += zp[((long)(bh*4 + qt))*4096 + i];
    Zi[(i>>6)*PST + (i&63)] = zs * Ss[i>>6];
  }
  __syncthreads();
  mm_nn8(Ai, Zi, Ci, t);
  __syncthreads();
  for (int i = t; i < 4096; i += 512) { const int r = i>>6, cc = i&63; w2t[(long)bh*4096 + cc*64 + r] = f2b(Ci[r*PST + cc]); }
}

// ---------------- out_h = softmax(q @ k_l^T) @ W2, fused, writes attnout bf16 ----------------
#define P1ST 144   /* bytes per P row */
__global__ __launch_bounds__(256) void k_attn1(const u16* __restrict__ q, const u16* __restrict__ klb,
                                               const u16* __restrict__ w2t, u16* __restrict__ ao) {
  __shared__ __align__(16) u16 Pl[4][64][72];
  const int bx = blockIdx.x, bh = bx >> 4, tt = bx & 15;
  const int b = bh >> 4, h = bh & 15;
  const int t = threadIdx.x, w = t >> 6, lane = t & 63;
  const int c = lane & 15, g = lane >> 4;
  const int tok0 = tt*256 + w*64;
  const u16* qp  = q + ((long)bh*NTOK + tok0)*DH;
  const u16* klp = klb + (long)bh*4096;
  const u16* wp  = w2t + (long)bh*4096;
  char* pbase = (char*)&Pl[w][0][0];

  s16x8 aq[4][2], kb[4][2], wb[4][2];
  #pragma unroll
  for (int i = 0; i < 4; ++i)
    #pragma unroll
    for (int ks = 0; ks < 2; ++ks) {
      aq[i][ks] = ld8(qp + (long)(i*16 + c)*DH + ks*32 + g*8);
      kb[i][ks] = ld8(klp + (i*16 + c)*64 + ks*32 + g*8);
      wb[i][ks] = ld8(wp  + (i*16 + c)*64 + ks*32 + g*8);
    }
  f32x4 sacc[4][4] = {};
  #pragma unroll
  for (int ks = 0; ks < 2; ++ks)
    #pragma unroll
    for (int mi = 0; mi < 4; ++mi)
      #pragma unroll
      for (int ni = 0; ni < 4; ++ni)
        sacc[mi][ni] = __builtin_amdgcn_mfma_f32_16x16x32_bf16(aq[mi][ks], kb[ni][ks], sacc[mi][ni], 0, 0, 0);

  float rs[4][4];
  #pragma unroll
  for (int mi = 0; mi < 4; ++mi)
    #pragma unroll
    for (int r = 0; r < 4; ++r) {
      const int row = mi*16 + g*4 + r;
      char* base = pbase + row*P1ST;
      float ssum = 0.f;
      #pragma unroll
      for (int ni = 0; ni < 4; ++ni) {
        const float p = __expf(sacc[mi][ni][r]);
        ssum += p;
        *(u16*)(base + (ni*16 + c)*2) = f2b(p);
      }
      ssum += __shfl_xor(ssum, 1); ssum += __shfl_xor(ssum, 2);
      ssum += __shfl_xor(ssum, 4); ssum += __shfl_xor(ssum, 8);
      rs[mi][r] = ssum;
    }
  __builtin_amdgcn_s_barrier();   // intra-wave store->read ordering
  s16x8 pa[4][2];
  #pragma unroll
  for (int mi = 0; mi < 4; ++mi)
    #pragma unroll
    for (int ks = 0; ks < 2; ++ks)
      pa[mi][ks] = *(const s16x8*)(pbase + (mi*16 + c)*P1ST + ks*64 + g*16);
  f32x4 oacc[4][4] = {};
  #pragma unroll
  for (int ks = 0; ks < 2; ++ks)
    #pragma unroll
    for (int mi = 0; mi < 4; ++mi)
      #pragma unroll
      for (int ni = 0; ni < 4; ++ni)
        oacc[mi][ni] = __builtin_amdgcn_mfma_f32_16x16x32_bf16(pa[mi][ks], wb[ni][ks], oacc[mi][ni], 0, 0, 0);

  u16* op = ao + (long)b*NTOK*DM + (long)h*64;
  #pragma unroll
  for (int mi = 0; mi < 4; ++mi)
    #pragma unroll
    for (int r = 0; r < 4; ++r) {
      const int tok = tok0 + mi*16 + g*4 + r;
      const float inv = 1.0f / rs[mi][r];
      #pragma unroll
      for (int ni = 0; ni < 4; ++ni)
        op[(long)tok*DM + ni*16 + c] = f2b(oacc[mi][ni][r] * inv);
    }
}

extern "C" void kernel_launch(void* const* d_in, const int* in_sizes, int n_in,
                              void* d_out, int out_size, void* d_ws, size_t ws_size,
                              hipStream_t stream) {
  const float* hs   = (const float*)d_in[0];
  const float* Wqkv = (const float*)d_in[1];
  const float* bqkv = (const float*)d_in[2];
  const float* Wout = (const float*)d_in[3];
  const float* bout = (const float*)d_in[4];
  float* out = (float*)d_out;
  char* w = (char*)d_ws;

  u16*  Xb    = (u16*)(w);                 // 32MB; free after QKV gemm
  float* zp   = (float*)(w);               // aliases Xb: written by attn3v_p (after gemm0)
  float* sp   = (float*)(w + 4194304L);    // within Xb region
  u16*  WqkvT = (u16*)(w + 33554432L);
  u16*  WoutT = (u16*)(w + 39845888L);
  u16*  q     = (u16*)(w + 41943040L);
  float* psum = (float*)(w + 41943040L);   // aliases q: consumed by k_lreduce before gemm writes q
  u16*  k     = (u16*)(w + 75497472L);
  u16*  v     = (u16*)(w + 109051904L);
  u16*  vt    = (u16*)(w + 142606336L);
  float* Xl   = (float*)(w + 142606336L);  // aliases vt: consumed before k_vtrans writes
  float* qlf  = (float*)(w + 176160768L);
  float* klf  = (float*)(w + 177209344L);
  u16*  qlb   = (u16*)(w + 178257920L);
  u16*  klb   = (u16*)(w + 178782208L);
  float* a2i  = (float*)(w + 179306496L);
  u16*  w2t   = (u16*)(w + 181403648L);
  u16*  ao    = (u16*)(w + 181927936L);

  k_cvt_xl<<<dim3(256,4), 256, 0, stream>>>(hs, Xb, Xl);
  k_cvt_t<<<dim3(48,16), 256, 0, stream>>>(Wqkv, WqkvT, 1024, 3072);
  k_cvt_t<<<dim3(16,16), 256, 0, stream>>>(Wout, WoutT, 1024, 1024);
  k_lproj2<<<dim3(8,8,8), 256, 0, stream>>>(Xl, Wqkv, psum);
  k_lreduce<<<2048, 256, 0, stream>>>(psum, bqkv, qlf, klf, qlb, klb);
  k_gemm256<0><<<dim3(64,12), 512, 0, stream>>>(Xb, WqkvT, bqkv, 3072, nullptr, q, k, v);
  k_vtrans<<<4096, 256, 0, stream>>>(v, vt);
  k_pinv<<<64, 512, 0, stream>>>(qlf, klf, a2i);
  k_attn3v_p<<<256, 256, 0, stream>>>(qlb, k, vt, zp, sp);
  k_w2<<<64, 512, 0, stream>>>(a2i, zp, sp, w2t);
  k_attn1<<<1024, 256, 0, stream>>>(q, klb, w2t, ao);
  k_gemm256<1><<<dim3(64,4), 512, 0, stream>>>(ao, WoutT, bout, 1024, out, nullptr, nullptr, nullptr);
}

// Round 9
// 369.512 us; speedup vs baseline: 5.2708x; 5.2708x over previous
//
#include <hip/hip_runtime.h>
#include <cstdint>

typedef unsigned short u16;
typedef __attribute__((ext_vector_type(8))) short s16x8;
typedef __attribute__((ext_vector_type(4))) float f32x4;

#define NTOK 4096
#define DH   64
#define DM   1024
#define NH   16

static __device__ __forceinline__ float b2f(u16 u){ return __uint_as_float(((unsigned)u)<<16); }
static __device__ __forceinline__ u16 f2b(float f){
  unsigned u = __float_as_uint(f);
  return (u16)((u + 0x7FFFu + ((u>>16)&1u)) >> 16);   // RNE
}

static __device__ __forceinline__ void gload_lds16(const void* g, void* l) {
  __builtin_amdgcn_global_load_lds(
      (const __attribute__((address_space(1))) unsigned*)(uintptr_t)g,
      (__attribute__((address_space(3))) unsigned*)(uintptr_t)l, 16, 0, 0);
}

static __device__ __forceinline__ s16x8 ld8(const u16* p){ return *(const s16x8*)(const void*)p; }

// ---------------- fused: hs -> bf16 Xb  AND  landmark means Xl (fp32) ----------------
__global__ __launch_bounds__(256) void k_cvt_xl(const float* __restrict__ hs, u16* __restrict__ Xb,
                                                float* __restrict__ Xl) {
  const int grp = blockIdx.x;                 // b*64 + lm (64-token group)
  const int d = blockIdx.y*256 + threadIdx.x;
  const float* p = hs + (long)grp*64*DM + d;
  u16* xo = Xb + (long)grp*64*DM + d;
  float s = 0.f;
  #pragma unroll 8
  for (int i = 0; i < 64; ++i) {
    const float v = p[(long)i*DM];
    s += v;
    xo[(long)i*DM] = f2b(v);
  }
  Xl[(long)grp*DM + d] = s * (1.0f/64.0f);
}

// ---------------- convert+transpose: f32 [R][C] -> bf16 [C][R] ----------------
__global__ __launch_bounds__(256) void k_cvt_t(const float* __restrict__ in, u16* __restrict__ out, int R, int C) {
  __shared__ float tile[64][65];
  const int tc = blockIdx.x, tr = blockIdx.y;
  const int t = threadIdx.x, cx = t & 63, ry = t >> 6;
  #pragma unroll
  for (int p = 0; p < 16; ++p) {
    const int row = p*4 + ry;
    tile[row][cx] = in[(long)(tr*64 + row)*C + tc*64 + cx];
  }
  __syncthreads();
  #pragma unroll
  for (int p = 0; p < 16; ++p) {
    const int orow = p*4 + ry;
    out[(long)(tc*64 + orow)*R + tr*64 + cx] = f2b(tile[cx][orow]);
  }
}

// ---------------- fp32 projection, K-split: psum[z][row][col] partials ----------------
__global__ __launch_bounds__(256) void k_lproj2(const float* __restrict__ Xl, const float* __restrict__ Wqkv,
                                                float* __restrict__ psum) {
  __shared__ __align__(16) float Xs[32][68];
  const int t = threadIdx.x;
  const int wcol = blockIdx.x*256 + t;    // 0..2047
  const int r0 = blockIdx.y*32;
  const int kbase = blockIdx.z*128;
  float acc[32];
  #pragma unroll
  for (int r = 0; r < 32; ++r) acc[r] = 0.f;
  for (int k0 = kbase; k0 < kbase + 128; k0 += 64) {
    __syncthreads();
    for (int idx = t; idx < 2048; idx += 256)
      Xs[idx>>6][idx&63] = Xl[(long)(r0 + (idx>>6))*DM + k0 + (idx&63)];
    __syncthreads();
    for (int kk = 0; kk < 64; kk += 4) {
      f32x4 wv;
      #pragma unroll
      for (int j = 0; j < 4; ++j) wv[j] = Wqkv[(long)(k0+kk+j)*3072 + wcol];
      #pragma unroll
      for (int r = 0; r < 32; ++r) {
        const f32x4 xv = *(const f32x4*)&Xs[r][kk];
        acc[r] += xv[0]*wv[0] + xv[1]*wv[1] + xv[2]*wv[2] + xv[3]*wv[3];
      }
    }
  }
  float* po = psum + ((long)blockIdx.z*256 + r0)*2048 + wcol;
  #pragma unroll
  for (int r = 0; r < 32; ++r) po[(long)r*2048] = acc[r];
}

// ---------------- reduce K-slices + bias + scale -> qlf/klf/qlb/klb ----------------
__global__ __launch_bounds__(256) void k_lreduce(const float* __restrict__ psum, const float* __restrict__ bqkv,
                                                 float* __restrict__ qlf, float* __restrict__ klf,
                                                 u16* __restrict__ qlb, u16* __restrict__ klb) {
  const long idx = (long)blockIdx.x*256 + threadIdx.x;   // 0..524287
  const int row = (int)(idx >> 11), col = (int)(idx & 2047);
  float s = 0.f;
  #pragma unroll
  for (int z = 0; z < 8; ++z) s += psum[((long)z*256 + row)*2048 + col];
  const int isq = (col < 1024) ? 1 : 0;
  float val = s + bqkv[col];
  if (isq) val *= 0.125f;
  const int b = row >> 6, lm = row & 63;
  const int c2 = col & 1023, h = c2 >> 6, dh = c2 & 63;
  const long o = (((long)b*NH + h)*64 + lm)*64 + dh;
  if (isq) { qlf[o] = val; qlb[o] = f2b(val); }
  else     { klf[o] = val; klb[o] = f2b(val); }
}

// ---------------- GEMM 256x256, BK=32, 8 waves, depth-2 LDS ring (64KB) ----------------
// r9: keep depth-2 ring (64KB LDS -> 2 blocks/CU possible) but restore
// __launch_bounds__(512,2): r8's (512,4) forced a 64-VGPR cap -> full scratch spill
// (FETCH 2GB, 1346us). With bound=2 the compiler emits ~116 VGPR <= 128, so the
// HW still co-resides 2 blocks/CU (LDS 2x64=128<=160KB, VGPR fits) without spill.
// Ledger: stage(kt+1)->buf[(kt+1)&1] at top of kt (its reads finished at barrier kt-1);
//   lgkmcnt(0) drains buf[kt&1] reads, vmcnt(0) confirms stage(kt+1) landed, then barrier.
// LDS swizzle (r5-verified): source chunk ^ (row>>1)&3, read offset g ^ (c>>1)&3.
template<int EPI>
__global__ __launch_bounds__(512, 2) void k_gemm256(
    const u16* __restrict__ A, const u16* __restrict__ Bt, const float* __restrict__ bias,
    int N, float* __restrict__ outF, u16* __restrict__ outQ, u16* __restrict__ outK, u16* __restrict__ outV)
{
  __shared__ __align__(16) u16 lds[2*16384];
  const int K = 1024;
  const int t = threadIdx.x;
  const int lane = t & 63;
  const int wid = t >> 6;
  const int c = lane & 15, g = lane >> 4;
  const int wm = wid >> 2, wn = wid & 3;
  // XCD-aware remap (bijective; neutral-to-positive)
  const int fid = blockIdx.y*64 + blockIdx.x;
  const int nbx = ((fid & 7) << 3) | ((fid >> 3) & 7);
  const int nby = fid >> 6;
  const long arow0 = (long)nbx * 256;
  const long brow0 = (long)nby * 256;
  char* ldsb = (char*)lds;

  const int srow = t >> 2;
  const int schunk = (t & 3) ^ ((srow >> 1) & 3);
  const u16* gA0 = A  + (arow0 + srow)*K       + schunk*8;
  const u16* gA1 = A  + (arow0 + 128 + srow)*K + schunk*8;
  const u16* gB0 = Bt + (brow0 + srow)*K       + schunk*8;
  const u16* gB1 = Bt + (brow0 + 128 + srow)*K + schunk*8;
  const int dstoff = t*16;

#define STAGE_A(kt) { char* bse = ldsb + ((kt)&1)*32768; \
    gload_lds16(gA0 + (kt)*32, bse + dstoff); \
    gload_lds16(gA1 + (kt)*32, bse + 8192 + dstoff); }
#define STAGE_B(kt) { char* bse = ldsb + ((kt)&1)*32768 + 16384; \
    gload_lds16(gB0 + (kt)*32, bse + dstoff); \
    gload_lds16(gB1 + (kt)*32, bse + 8192 + dstoff); }

  const int gs = g ^ ((c >> 1) & 3);
  int aoff[2][4], boff[4];
  #pragma unroll
  for (int mi = 0; mi < 4; ++mi) {
    aoff[0][mi] = (0*128 + wm*64 + mi*16 + c)*64 + gs*16;
    aoff[1][mi] = (1*128 + wm*64 + mi*16 + c)*64 + gs*16;
    boff[mi]    = 16384 + (wn*64 + mi*16 + c)*64 + gs*16;
  }

  f32x4 acc0[4][4] = {};
  f32x4 acc1[4][4] = {};

  // prologue: stage tile 0, wait, read first af/bfr
  STAGE_A(0); STAGE_B(0);
  asm volatile("s_waitcnt vmcnt(0)" ::: "memory");
  __builtin_amdgcn_s_barrier();

  s16x8 af[4], bfr[4], af2[4];
  #pragma unroll
  for (int mi = 0; mi < 4; ++mi) af[mi]  = *(const s16x8*)(ldsb + aoff[0][mi]);
  #pragma unroll
  for (int ni = 0; ni < 4; ++ni) bfr[ni] = *(const s16x8*)(ldsb + boff[ni]);

  for (int kt = 0; kt < 32; ++kt) {
    char* buf  = ldsb + (kt&1)*32768;
    char* bufn = ldsb + ((kt+1)&1)*32768;
    if (kt + 1 < 32) { STAGE_A(kt+1) STAGE_B(kt+1) }
    // drain af/bfr reads (issued last iter), then issue af2 under acc0's MFMAs
    asm volatile("s_waitcnt lgkmcnt(0)" ::: "memory");
    __builtin_amdgcn_sched_barrier(0);
    #pragma unroll
    for (int mi = 0; mi < 4; ++mi) af2[mi] = *(const s16x8*)(buf + aoff[1][mi]);
    __builtin_amdgcn_sched_barrier(0);
    __builtin_amdgcn_s_setprio(1);
    #pragma unroll
    for (int mi = 0; mi < 4; ++mi)
      #pragma unroll
      for (int ni = 0; ni < 4; ++ni)
        acc0[mi][ni] = __builtin_amdgcn_mfma_f32_16x16x32_bf16(af[mi], bfr[ni], acc0[mi][ni], 0, 0, 0);
    __builtin_amdgcn_s_setprio(0);
    // drain af2 reads; ensure stage(kt+1) landed; barrier; then prefetch next-tile frags
    asm volatile("s_waitcnt lgkmcnt(0)" ::: "memory");
    __builtin_amdgcn_sched_barrier(0);
    if (kt + 1 < 32) { asm volatile("s_waitcnt vmcnt(0)" ::: "memory"); }
    __builtin_amdgcn_s_barrier();
    s16x8 nf[4], nb[4];
    if (kt < 31) {
      #pragma unroll
      for (int mi = 0; mi < 4; ++mi) nf[mi] = *(const s16x8*)(bufn + aoff[0][mi]);
      #pragma unroll
      for (int ni = 0; ni < 4; ++ni) nb[ni] = *(const s16x8*)(bufn + boff[ni]);
    }
    __builtin_amdgcn_sched_barrier(0);
    __builtin_amdgcn_s_setprio(1);
    #pragma unroll
    for (int mi = 0; mi < 4; ++mi)
      #pragma unroll
      for (int ni = 0; ni < 4; ++ni)
        acc1[mi][ni] = __builtin_amdgcn_mfma_f32_16x16x32_bf16(af2[mi], bfr[ni], acc1[mi][ni], 0, 0, 0);
    __builtin_amdgcn_s_setprio(0);
    if (kt < 31) {
      #pragma unroll
      for (int mi = 0; mi < 4; ++mi) { af[mi] = nf[mi]; bfr[mi] = nb[mi]; }
    }
  }
#undef STAGE_A
#undef STAGE_B

  if (EPI == 0) {
    const int tensor = (int)(brow0 >> 10);
    u16* dst = (tensor == 0) ? outQ : (tensor == 1) ? outK : outV;
    const float mul = (tensor == 0) ? 0.125f : 1.0f;
    #pragma unroll
    for (int ph = 0; ph < 2; ++ph)
      #pragma unroll
      for (int mi = 0; mi < 4; ++mi) {
        const int rowb = ph*128 + wm*64 + mi*16 + g*4;
        #pragma unroll
        for (int ni = 0; ni < 4; ++ni) {
          const long gcol = brow0 + wn*64 + ni*16 + c;
          const int c2 = (int)(gcol & 1023);
          const int head = c2 >> 6, dh = c2 & 63;
          const float bv = bias[gcol];
          const f32x4 a = ph ? acc1[mi][ni] : acc0[mi][ni];
          #pragma unroll
          for (int r = 0; r < 4; ++r) {
            const long grow = arow0 + rowb + r;
            const int b = (int)(grow >> 12), tok = (int)(grow & 4095);
            dst[(((long)b*NH + head)*NTOK + tok)*DH + dh] = f2b((a[r] + bv)*mul);
          }
        }
      }
  } else {
    #pragma unroll
    for (int ph = 0; ph < 2; ++ph)
      #pragma unroll
      for (int mi = 0; mi < 4; ++mi) {
        const int rowb = ph*128 + wm*64 + mi*16 + g*4;
        #pragma unroll
        for (int ni = 0; ni < 4; ++ni) {
          const long gcol = brow0 + wn*64 + ni*16 + c;
          const float bv = bias[gcol];
          const f32x4 a = ph ? acc1[mi][ni] : acc0[mi][ni];
          #pragma unroll
          for (int r = 0; r < 4; ++r) {
            const long grow = arow0 + rowb + r;
            outF[grow*N + gcol] = a[r] + bv;
          }
        }
      }
  }
}

// ---------------- v transpose: [bh][tok][dh] -> [bh][dh][tok] ----------------
__global__ __launch_bounds__(256) void k_vtrans(const u16* __restrict__ v, u16* __restrict__ vt) {
  __shared__ u16 tile[64][65];
  const int bh = blockIdx.x >> 6, tt = blockIdx.x & 63;
  const int t = threadIdx.x, cx = t & 63, ry = t >> 6;
  const u16* vp = v + ((long)bh*NTOK + tt*64)*DH;
  #pragma unroll
  for (int p = 0; p < 16; ++p) { const int row = p*4 + ry; tile[row][cx] = vp[row*DH + cx]; }
  __syncthreads();
  u16* op = vt + (long)bh*DH*NTOK + tt*64;
  #pragma unroll
  for (int p = 0; p < 16; ++p) { const int orow = p*4 + ry; op[(long)orow*NTOK + cx] = tile[cx][orow]; }
}

// ---------------- fp32 LDS 64x64 matmul helpers, 512 threads (8 cols/thread) ----------------
#define PST 68
static __device__ __forceinline__ void mm_nn8(const float* A, const float* B, float* C, int t) {
  const int lane = t & 63, j0 = (t >> 6) << 3;
  float acc[8];
  #pragma unroll
  for (int j = 0; j < 8; ++j) acc[j] = 0.f;
  for (int k = 0; k < 64; k += 4) {
    const f32x4 a4 = *(const f32x4*)&A[lane*PST + k];
    #pragma unroll
    for (int dk = 0; dk < 4; ++dk) {
      const float a = a4[dk];
      const float* br = &B[(k + dk)*PST + j0];
      const f32x4 b0 = *(const f32x4*)(br);
      const f32x4 b1 = *(const f32x4*)(br + 4);
      #pragma unroll
      for (int qq = 0; qq < 4; ++qq) { acc[qq] += a*b0[qq]; acc[4+qq] += a*b1[qq]; }
    }
  }
  #pragma unroll
  for (int j = 0; j < 8; ++j) C[lane*PST + j0 + j] = acc[j];
}
static __device__ __forceinline__ void mm_nt8(const float* A, const float* B, float* C, int t) {
  const int lane = t & 63, j0 = (t >> 6) << 3;
  float acc[8];
  #pragma unroll
  for (int j = 0; j < 8; ++j) acc[j] = 0.f;
  for (int k = 0; k < 64; k += 4) {
    const f32x4 a4 = *(const f32x4*)&A[lane*PST + k];
    #pragma unroll
    for (int jj = 0; jj < 8; ++jj) {
      const f32x4 b4 = *(const f32x4*)&B[(j0 + jj)*PST + k];
      acc[jj] += a4[0]*b4[0] + a4[1]*b4[1] + a4[2]*b4[2] + a4[3]*b4[3];
    }
  }
  #pragma unroll
  for (int j = 0; j < 8; ++j) C[lane*PST + j0 + j] = acc[j];
}

// ---------------- sim2 + softmax + Newton-Schulz pinv (all fp32, 512 thr) ----------------
__global__ __launch_bounds__(512) void k_pinv(const float* __restrict__ qlf, const float* __restrict__ klf,
                                              float* __restrict__ a2inv) {
  __shared__ __align__(16) float Xb[64*PST];
  __shared__ __align__(16) float Vb[64*PST];
  __shared__ __align__(16) float T1[64*PST];
  __shared__ __align__(16) float T2[64*PST];
  __shared__ __align__(16) float T3[64*PST];
  const int bh = blockIdx.x, t = threadIdx.x;
  const float* ql = qlf + (long)bh*4096;
  const float* kl = klf + (long)bh*4096;
  for (int i = t; i < 4096; i += 512) { T1[(i>>6)*PST + (i&63)] = ql[i]; T2[(i>>6)*PST + (i&63)] = kl[i]; }
  __syncthreads();
  mm_nt8(T1, T2, Xb, t);          // sim2 = q_l @ k_l^T
  __syncthreads();
  if (t < 64) {                   // row softmax (precise exp on the chaotic path)
    float mx = -1e30f;
    for (int j = 0; j < 64; ++j) mx = fmaxf(mx, Xb[t*PST + j]);
    float s = 0.f;
    for (int j = 0; j < 64; ++j) { const float e = expf(Xb[t*PST + j] - mx); Xb[t*PST + j] = e; s += e; }
    const float inv = 1.0f/s;
    for (int j = 0; j < 64; ++j) Xb[t*PST + j] *= inv;
  }
  __syncthreads();
  for (int i = t; i < 4096; i += 512) { const int r = i>>6, cc = i&63; Vb[r*PST+cc] = Xb[r*PST+cc]; }
  __syncthreads();
  for (int it = 0; it < 6; ++it) {
    mm_nn8(Xb, Vb, T1, t);  __syncthreads();                 // KV
    for (int i = t; i < 4096; i += 512) { const int r=i>>6, cc=i&63; T2[r*PST+cc] = (r==cc?7.0f:0.0f) - T1[r*PST+cc]; }
    __syncthreads();
    mm_nn8(T1, T2, T3, t);  __syncthreads();                 // KV@(7I-KV)
    for (int i = t; i < 4096; i += 512) { const int r=i>>6, cc=i&63; T2[r*PST+cc] = (r==cc?15.0f:0.0f) - T3[r*PST+cc]; }
    __syncthreads();
    mm_nn8(T1, T2, T3, t);  __syncthreads();                 // KV@(15I-...)
    for (int i = t; i < 4096; i += 512) { const int r=i>>6, cc=i&63; T2[r*PST+cc] = (r==cc?13.0f:0.0f) - T3[r*PST+cc]; }
    __syncthreads();
    mm_nn8(Vb, T2, T3, t);  __syncthreads();                 // V@(13I-...)
    for (int i = t; i < 4096; i += 512) { const int r=i>>6, cc=i&63; Vb[r*PST+cc] = 0.25f*T3[r*PST+cc]; }
    __syncthreads();
  }
  for (int i = t; i < 4096; i += 512) a2inv[(long)bh*4096 + i] = Vb[(i>>6)*PST + (i&63)];
}

// ---------------- attn3 @ v partials: 4 blocks per (b,h), 1024 tokens each ----------------
__global__ __launch_bounds__(256) void k_attn3v_p(const u16* __restrict__ qlb, const u16* __restrict__ kk,
                                                  const u16* __restrict__ vt,
                                                  float* __restrict__ zp, float* __restrict__ sp) {
  __shared__ __align__(16) float Zl[4][64][64];
  __shared__ float Sl[4][64];
  __shared__ __align__(16) u16 Pl[4][64][40];   // rows padded to 80B (32 cols used)
  const int bh = blockIdx.x >> 2, qt = blockIdx.x & 3;
  const int t = threadIdx.x, w = t >> 6, lane = t & 63;
  const int c = lane & 15, g = lane >> 4;

  s16x8 aq[4][2];
  const u16* qlp = qlb + (long)bh*4096;
  #pragma unroll
  for (int mi = 0; mi < 4; ++mi)
    #pragma unroll
    for (int ks = 0; ks < 2; ++ks)
      aq[mi][ks] = ld8(qlp + (mi*16 + c)*64 + ks*32 + g*8);

  f32x4 zacc[4][4] = {};
  float sl[4][4] = {};
  const u16* kp = kk + (long)bh*NTOK*DH;
  const u16* vp = vt + (long)bh*DH*NTOK;
  char* pbase = (char*)&Pl[w][0][0];
  const int tok00 = qt*1024 + w*256;

  for (int it = 0; it < 8; ++it) {
    const int t0 = tok00 + it*32;
    f32x4 sacc[4][2] = {};
    s16x8 kb[2][2];
    #pragma unroll
    for (int cg = 0; cg < 2; ++cg)
      #pragma unroll
      for (int ks = 0; ks < 2; ++ks)
        kb[cg][ks] = ld8(kp + (long)(t0 + cg*16 + c)*64 + ks*32 + g*8);
    #pragma unroll
    for (int cg = 0; cg < 2; ++cg)
      #pragma unroll
      for (int ks = 0; ks < 2; ++ks)
        #pragma unroll
        for (int mi = 0; mi < 4; ++mi)
          sacc[mi][cg] = __builtin_amdgcn_mfma_f32_16x16x32_bf16(aq[mi][ks], kb[cg][ks], sacc[mi][cg], 0, 0, 0);
    #pragma unroll
    for (int mi = 0; mi < 4; ++mi)
      #pragma unroll
      for (int r = 0; r < 4; ++r) {
        const int row = mi*16 + g*4 + r;
        const float p0 = __expf(sacc[mi][0][r]);
        const float p1 = __expf(sacc[mi][1][r]);
        sl[mi][r] += p0 + p1;
        char* base = pbase + row*80;
        *(u16*)(base + c*2)      = f2b(p0);
        *(u16*)(base + 32 + c*2) = f2b(p1);
      }
    s16x8 pa[4];
    #pragma unroll
    for (int mi = 0; mi < 4; ++mi) pa[mi] = *(const s16x8*)(pbase + (mi*16 + c)*80 + g*16);
    #pragma unroll
    for (int ni = 0; ni < 4; ++ni) {
      const s16x8 vb = ld8(vp + (long)(ni*16 + c)*NTOK + t0 + g*8);
      #pragma unroll
      for (int mi = 0; mi < 4; ++mi)
        zacc[mi][ni] = __builtin_amdgcn_mfma_f32_16x16x32_bf16(pa[mi], vb, zacc[mi][ni], 0, 0, 0);
    }
  }
  #pragma unroll
  for (int mi = 0; mi < 4; ++mi)
    #pragma unroll
    for (int r = 0; r < 4; ++r) {
      float s = sl[mi][r];
      s += __shfl_xor(s, 1); s += __shfl_xor(s, 2); s += __shfl_xor(s, 4); s += __shfl_xor(s, 8);
      sl[mi][r] = s;
    }
  #pragma unroll
  for (int mi = 0; mi < 4; ++mi)
    #pragma unroll
    for (int ni = 0; ni < 4; ++ni)
      #pragma unroll
      for (int r = 0; r < 4; ++r)
        Zl[w][mi*16 + g*4 + r][ni*16 + c] = zacc[mi][ni][r];
  if (c == 0)
    #pragma unroll
    for (int mi = 0; mi < 4; ++mi)
      #pragma unroll
      for (int r = 0; r < 4; ++r)
        Sl[w][mi*16 + g*4 + r] = sl[mi][r];
  __syncthreads();
  float* zpp = zp + (long)blockIdx.x*4096;
  for (int i = t; i < 4096; i += 256) {
    const int row = i >> 6, dh = i & 63;
    zpp[i] = Zl[0][row][dh] + Zl[1][row][dh] + Zl[2][row][dh] + Zl[3][row][dh];
  }
  if (t < 64) sp[(long)blockIdx.x*64 + t] = Sl[0][t] + Sl[1][t] + Sl[2][t] + Sl[3][t];
}

// ---------------- fused: z-reduce + W2^T = (attn2inv @ z)^T  (bf16 [dh][lm], 512 thr) ----------------
__global__ __launch_bounds__(512) void k_w2(const float* __restrict__ a2inv,
                                            const float* __restrict__ zp, const float* __restrict__ sp,
                                            u16* __restrict__ w2t) {
  __shared__ __align__(16) float Ai[64*PST];
  __shared__ __align__(16) float Zi[64*PST];
  __shared__ __align__(16) float Ci[64*PST];
  __shared__ float Ss[64];
  const int bh = blockIdx.x, t = threadIdx.x;
  if (t < 64) {
    float ss = 0.f;
    #pragma unroll
    for (int qt = 0; qt < 4; ++qt) ss += sp[(long)(bh*4 + qt)*64 + t];
    Ss[t] = 1.0f / ss;
  }
  for (int i = t; i < 4096; i += 512)
    Ai[(i>>6)*PST + (i&63)] = a2inv[(long)bh*4096 + i];
  __syncthreads();
  for (int i = t; i < 4096; i += 512) {
    float zs = 0.f;
    #pragma unroll
    for (int qt = 0; qt < 4; ++qt) zs += zp[((long)(bh*4 + qt))*4096 + i];
    Zi[(i>>6)*PST + (i&63)] = zs * Ss[i>>6];
  }
  __syncthreads();
  mm_nn8(Ai, Zi, Ci, t);
  __syncthreads();
  for (int i = t; i < 4096; i += 512) { const int r = i>>6, cc = i&63; w2t[(long)bh*4096 + cc*64 + r] = f2b(Ci[r*PST + cc]); }
}

// ---------------- out_h = softmax(q @ k_l^T) @ W2, fused, writes attnout bf16 ----------------
#define P1ST 144   /* bytes per P row */
__global__ __launch_bounds__(256) void k_attn1(const u16* __restrict__ q, const u16* __restrict__ klb,
                                               const u16* __restrict__ w2t, u16* __restrict__ ao) {
  __shared__ __align__(16) u16 Pl[4][64][72];
  const int bx = blockIdx.x, bh = bx >> 4, tt = bx & 15;
  const int b = bh >> 4, h = bh & 15;
  const int t = threadIdx.x, w = t >> 6, lane = t & 63;
  const int c = lane & 15, g = lane >> 4;
  const int tok0 = tt*256 + w*64;
  const u16* qp  = q + ((long)bh*NTOK + tok0)*DH;
  const u16* klp = klb + (long)bh*4096;
  const u16* wp  = w2t + (long)bh*4096;
  char* pbase = (char*)&Pl[w][0][0];

  s16x8 aq[4][2], kb[4][2], wb[4][2];
  #pragma unroll
  for (int i = 0; i < 4; ++i)
    #pragma unroll
    for (int ks = 0; ks < 2; ++ks) {
      aq[i][ks] = ld8(qp + (long)(i*16 + c)*DH + ks*32 + g*8);
      kb[i][ks] = ld8(klp + (i*16 + c)*64 + ks*32 + g*8);
      wb[i][ks] = ld8(wp  + (i*16 + c)*64 + ks*32 + g*8);
    }
  f32x4 sacc[4][4] = {};
  #pragma unroll
  for (int ks = 0; ks < 2; ++ks)
    #pragma unroll
    for (int mi = 0; mi < 4; ++mi)
      #pragma unroll
      for (int ni = 0; ni < 4; ++ni)
        sacc[mi][ni] = __builtin_amdgcn_mfma_f32_16x16x32_bf16(aq[mi][ks], kb[ni][ks], sacc[mi][ni], 0, 0, 0);

  float rs[4][4];
  #pragma unroll
  for (int mi = 0; mi < 4; ++mi)
    #pragma unroll
    for (int r = 0; r < 4; ++r) {
      const int row = mi*16 + g*4 + r;
      char* base = pbase + row*P1ST;
      float ssum = 0.f;
      #pragma unroll
      for (int ni = 0; ni < 4; ++ni) {
        const float p = __expf(sacc[mi][ni][r]);
        ssum += p;
        *(u16*)(base + (ni*16 + c)*2) = f2b(p);
      }
      ssum += __shfl_xor(ssum, 1); ssum += __shfl_xor(ssum, 2);
      ssum += __shfl_xor(ssum, 4); ssum += __shfl_xor(ssum, 8);
      rs[mi][r] = ssum;
    }
  __builtin_amdgcn_s_barrier();   // intra-wave store->read ordering
  s16x8 pa[4][2];
  #pragma unroll
  for (int mi = 0; mi < 4; ++mi)
    #pragma unroll
    for (int ks = 0; ks < 2; ++ks)
      pa[mi][ks] = *(const s16x8*)(pbase + (mi*16 + c)*P1ST + ks*64 + g*16);
  f32x4 oacc[4][4] = {};
  #pragma unroll
  for (int ks = 0; ks < 2; ++ks)
    #pragma unroll
    for (int mi = 0; mi < 4; ++mi)
      #pragma unroll
      for (int ni = 0; ni < 4; ++ni)
        oacc[mi][ni] = __builtin_amdgcn_mfma_f32_16x16x32_bf16(pa[mi][ks], wb[ni][ks], oacc[mi][ni], 0, 0, 0);

  u16* op = ao + (long)b*NTOK*DM + (long)h*64;
  #pragma unroll
  for (int mi = 0; mi < 4; ++mi)
    #pragma unroll
    for (int r = 0; r < 4; ++r) {
      const int tok = tok0 + mi*16 + g*4 + r;
      const float inv = 1.0f / rs[mi][r];
      #pragma unroll
      for (int ni = 0; ni < 4; ++ni)
        op[(long)tok*DM + ni*16 + c] = f2b(oacc[mi][ni][r] * inv);
    }
}

extern "C" void kernel_launch(void* const* d_in, const int* in_sizes, int n_in,
                              void* d_out, int out_size, void* d_ws, size_t ws_size,
                              hipStream_t stream) {
  const float* hs   = (const float*)d_in[0];
  const float* Wqkv = (const float*)d_in[1];
  const float* bqkv = (const float*)d_in[2];
  const float* Wout = (const float*)d_in[3];
  const float* bout = (const float*)d_in[4];
  float* out = (float*)d_out;
  char* w = (char*)d_ws;

  u16*  Xb    = (u16*)(w);                 // 32MB; free after QKV gemm
  float* zp   = (float*)(w);               // aliases Xb: written by attn3v_p (after gemm0)
  float* sp   = (float*)(w + 4194304L);    // within Xb region
  u16*  WqkvT = (u16*)(w + 33554432L);
  u16*  WoutT = (u16*)(w + 39845888L);
  u16*  q     = (u16*)(w + 41943040L);
  float* psum = (float*)(w + 41943040L);   // aliases q: consumed by k_lreduce before gemm writes q
  u16*  k     = (u16*)(w + 75497472L);
  u16*  v     = (u16*)(w + 109051904L);
  u16*  vt    = (u16*)(w + 142606336L);
  float* Xl   = (float*)(w + 142606336L);  // aliases vt: consumed before k_vtrans writes
  float* qlf  = (float*)(w + 176160768L);
  float* klf  = (float*)(w + 177209344L);
  u16*  qlb   = (u16*)(w + 178257920L);
  u16*  klb   = (u16*)(w + 178782208L);
  float* a2i  = (float*)(w + 179306496L);
  u16*  w2t   = (u16*)(w + 181403648L);
  u16*  ao    = (u16*)(w + 181927936L);

  k_cvt_xl<<<dim3(256,4), 256, 0, stream>>>(hs, Xb, Xl);
  k_cvt_t<<<dim3(48,16), 256, 0, stream>>>(Wqkv, WqkvT, 1024, 3072);
  k_cvt_t<<<dim3(16,16), 256, 0, stream>>>(Wout, WoutT, 1024, 1024);
  k_lproj2<<<dim3(8,8,8), 256, 0, stream>>>(Xl, Wqkv, psum);
  k_lreduce<<<2048, 256, 0, stream>>>(psum, bqkv, qlf, klf, qlb, klb);
  k_gemm256<0><<<dim3(64,12), 512, 0, stream>>>(Xb, WqkvT, bqkv, 3072, nullptr, q, k, v);
  k_vtrans<<<4096, 256, 0, stream>>>(v, vt);
  k_pinv<<<64, 512, 0, stream>>>(qlf, klf, a2i);
  k_attn3v_p<<<256, 256, 0, stream>>>(qlb, k, vt, zp, sp);
  k_w2<<<64, 512, 0, stream>>>(a2i, zp, sp, w2t);
  k_attn1<<<1024, 256, 0, stream>>>(q, klb, w2t, ao);
  k_gemm256<1><<<dim3(64,4), 512, 0, stream>>>(ao, WoutT, bout, 1024, out, nullptr, nullptr, nullptr);
}

// Round 10
// 356.545 us; speedup vs baseline: 5.4625x; 1.0364x over previous
//
#include <hip/hip_runtime.h>
#include <cstdint>

typedef unsigned short u16;
typedef __attribute__((ext_vector_type(8))) short s16x8;
typedef __attribute__((ext_vector_type(4))) float f32x4;

#define NTOK 4096
#define DH   64
#define DM   1024
#define NH   16

static __device__ __forceinline__ float b2f(u16 u){ return __uint_as_float(((unsigned)u)<<16); }
static __device__ __forceinline__ u16 f2b(float f){
  unsigned u = __float_as_uint(f);
  return (u16)((u + 0x7FFFu + ((u>>16)&1u)) >> 16);   // RNE
}

static __device__ __forceinline__ void gload_lds16(const void* g, void* l) {
  __builtin_amdgcn_global_load_lds(
      (const __attribute__((address_space(1))) unsigned*)(uintptr_t)g,
      (__attribute__((address_space(3))) unsigned*)(uintptr_t)l, 16, 0, 0);
}

static __device__ __forceinline__ s16x8 ld8(const u16* p){ return *(const s16x8*)(const void*)p; }

// ---------------- fused: hs -> bf16 Xb  AND  landmark means Xl (fp32) ----------------
__global__ __launch_bounds__(256) void k_cvt_xl(const float* __restrict__ hs, u16* __restrict__ Xb,
                                                float* __restrict__ Xl) {
  const int grp = blockIdx.x;
  const int d = blockIdx.y*256 + threadIdx.x;
  const float* p = hs + (long)grp*64*DM + d;
  u16* xo = Xb + (long)grp*64*DM + d;
  float s = 0.f;
  #pragma unroll 8
  for (int i = 0; i < 64; ++i) {
    const float v = p[(long)i*DM];
    s += v;
    xo[(long)i*DM] = f2b(v);
  }
  Xl[(long)grp*DM + d] = s * (1.0f/64.0f);
}

// ---------------- convert+transpose: f32 [R][C] -> bf16 [C][R] ----------------
__global__ __launch_bounds__(256) void k_cvt_t(const float* __restrict__ in, u16* __restrict__ out, int R, int C) {
  __shared__ float tile[64][65];
  const int tc = blockIdx.x, tr = blockIdx.y;
  const int t = threadIdx.x, cx = t & 63, ry = t >> 6;
  #pragma unroll
  for (int p = 0; p < 16; ++p) {
    const int row = p*4 + ry;
    tile[row][cx] = in[(long)(tr*64 + row)*C + tc*64 + cx];
  }
  __syncthreads();
  #pragma unroll
  for (int p = 0; p < 16; ++p) {
    const int orow = p*4 + ry;
    out[(long)(tc*64 + orow)*R + tr*64 + cx] = f2b(tile[cx][orow]);
  }
}

// ---------------- fp32 projection, K-split: psum[z][row][col] partials ----------------
__global__ __launch_bounds__(256) void k_lproj2(const float* __restrict__ Xl, const float* __restrict__ Wqkv,
                                                float* __restrict__ psum) {
  __shared__ __align__(16) float Xs[32][68];
  const int t = threadIdx.x;
  const int wcol = blockIdx.x*256 + t;    // 0..2047
  const int r0 = blockIdx.y*32;
  const int kbase = blockIdx.z*128;
  float acc[32];
  #pragma unroll
  for (int r = 0; r < 32; ++r) acc[r] = 0.f;
  for (int k0 = kbase; k0 < kbase + 128; k0 += 64) {
    __syncthreads();
    for (int idx = t; idx < 2048; idx += 256)
      Xs[idx>>6][idx&63] = Xl[(long)(r0 + (idx>>6))*DM + k0 + (idx&63)];
    __syncthreads();
    for (int kk = 0; kk < 64; kk += 4) {
      f32x4 wv;
      #pragma unroll
      for (int j = 0; j < 4; ++j) wv[j] = Wqkv[(long)(k0+kk+j)*3072 + wcol];
      #pragma unroll
      for (int r = 0; r < 32; ++r) {
        const f32x4 xv = *(const f32x4*)&Xs[r][kk];
        acc[r] += xv[0]*wv[0] + xv[1]*wv[1] + xv[2]*wv[2] + xv[3]*wv[3];
      }
    }
  }
  float* po = psum + ((long)blockIdx.z*256 + r0)*2048 + wcol;
  #pragma unroll
  for (int r = 0; r < 32; ++r) po[(long)r*2048] = acc[r];
}

// ---------------- reduce K-slices + bias + scale -> qlf/klf/qlb/klb ----------------
__global__ __launch_bounds__(256) void k_lreduce(const float* __restrict__ psum, const float* __restrict__ bqkv,
                                                 float* __restrict__ qlf, float* __restrict__ klf,
                                                 u16* __restrict__ qlb, u16* __restrict__ klb) {
  const long idx = (long)blockIdx.x*256 + threadIdx.x;
  const int row = (int)(idx >> 11), col = (int)(idx & 2047);
  float s = 0.f;
  #pragma unroll
  for (int z = 0; z < 8; ++z) s += psum[((long)z*256 + row)*2048 + col];
  const int isq = (col < 1024) ? 1 : 0;
  float val = s + bqkv[col];
  if (isq) val *= 0.125f;
  const int b = row >> 6, lm = row & 63;
  const int c2 = col & 1023, h = c2 >> 6, dh = c2 & 63;
  const long o = (((long)b*NH + h)*64 + lm)*64 + dh;
  if (isq) { qlf[o] = val; qlb[o] = f2b(val); }
  else     { klf[o] = val; klb[o] = f2b(val); }
}

// ---------------- GEMM 256x256, BK=32, 8 waves, 4-deep LDS ring, counted vmcnt ----------------
// r10: r6 ledger (proven fastest: stage kt+3 at tile top, vmcnt(8/4/0)+barrier at tile end)
// with FOUR phases of 8 MFMAs per K-tile (short lgkm waits, 1 gload/phase) and a single
// barrier per tile (mid-tile barrier protected nothing: stages go to buf (kt+3)&3).
// For EPI==0, the V third writes vt[bh][dh][tok] directly via per-wave LDS transpose
// in the epilogue (ring LDS is dead after the K-loop) -- replaces the k_vtrans kernel.
// LDS swizzle (r5-verified, conflicts==0): source chunk ^ (row>>1)&3, read g ^ (c>>1)&3.
template<int EPI>
__global__ __launch_bounds__(512, 2) void k_gemm256(
    const u16* __restrict__ A, const u16* __restrict__ Bt, const float* __restrict__ bias,
    int N, float* __restrict__ outF, u16* __restrict__ outQ, u16* __restrict__ outK, u16* __restrict__ outV)
{
  __shared__ __align__(16) u16 lds[4*16384];
  const int K = 1024;
  const int t = threadIdx.x;
  const int lane = t & 63;
  const int wid = t >> 6;
  const int c = lane & 15, g = lane >> 4;
  const int wm = wid >> 2, wn = wid & 3;
  const int fid = blockIdx.y*64 + blockIdx.x;
  const int nbx = ((fid & 7) << 3) | ((fid >> 3) & 7);
  const int nby = fid >> 6;
  const long arow0 = (long)nbx * 256;
  const long brow0 = (long)nby * 256;
  char* ldsb = (char*)lds;

  const int srow = t >> 2;
  const int schunk = (t & 3) ^ ((srow >> 1) & 3);
  const u16* gA0 = A  + (arow0 + srow)*K       + schunk*8;
  const u16* gA1 = A  + (arow0 + 128 + srow)*K + schunk*8;
  const u16* gB0 = Bt + (brow0 + srow)*K       + schunk*8;
  const u16* gB1 = Bt + (brow0 + 128 + srow)*K + schunk*8;
  const int dstoff = t*16;

#define GL_A0(kt) gload_lds16(gA0 + (kt)*32, ldsb + ((kt)&3)*32768 + dstoff);
#define GL_A1(kt) gload_lds16(gA1 + (kt)*32, ldsb + ((kt)&3)*32768 + 8192 + dstoff);
#define GL_B0(kt) gload_lds16(gB0 + (kt)*32, ldsb + ((kt)&3)*32768 + 16384 + dstoff);
#define GL_B1(kt) gload_lds16(gB1 + (kt)*32, ldsb + ((kt)&3)*32768 + 24576 + dstoff);

  const int gs = g ^ ((c >> 1) & 3);
  int aoff[2][4], boff[4];
  #pragma unroll
  for (int mi = 0; mi < 4; ++mi) {
    aoff[0][mi] = (0*128 + wm*64 + mi*16 + c)*64 + gs*16;
    aoff[1][mi] = (1*128 + wm*64 + mi*16 + c)*64 + gs*16;
    boff[mi]    = 16384 + (wn*64 + mi*16 + c)*64 + gs*16;
  }

  f32x4 acc0[4][4] = {};
  f32x4 acc1[4][4] = {};

  // prologue: stage K-tiles 0,1,2 (12 loads); retire tile 0 (keep 8 in flight)
  GL_A0(0) GL_A1(0) GL_B0(0) GL_B1(0)
  GL_A0(1) GL_A1(1) GL_B0(1) GL_B1(1)
  GL_A0(2) GL_A1(2) GL_B0(2) GL_B1(2)
  asm volatile("s_waitcnt vmcnt(8)" ::: "memory");
  __builtin_amdgcn_s_barrier();

  for (int kt = 0; kt < 32; ++kt) {
    char* buf = ldsb + (kt&3)*32768;
    s16x8 fa0, fa1, fb[4];
    // ---- phase 0: A rows 0-31 of band0, all B ----
    if (kt + 3 < 32) GL_A0(kt+3)
    fa0 = *(const s16x8*)(buf + aoff[0][0]);
    fa1 = *(const s16x8*)(buf + aoff[0][1]);
    #pragma unroll
    for (int ni = 0; ni < 4; ++ni) fb[ni] = *(const s16x8*)(buf + boff[ni]);
    asm volatile("s_waitcnt lgkmcnt(0)" ::: "memory");
    __builtin_amdgcn_sched_barrier(0);
    __builtin_amdgcn_s_setprio(1);
    #pragma unroll
    for (int ni = 0; ni < 4; ++ni) acc0[0][ni] = __builtin_amdgcn_mfma_f32_16x16x32_bf16(fa0, fb[ni], acc0[0][ni], 0, 0, 0);
    #pragma unroll
    for (int ni = 0; ni < 4; ++ni) acc0[1][ni] = __builtin_amdgcn_mfma_f32_16x16x32_bf16(fa1, fb[ni], acc0[1][ni], 0, 0, 0);
    __builtin_amdgcn_s_setprio(0);
    // ---- phase 1: A rows 32-63 of band0 ----
    if (kt + 3 < 32) GL_A1(kt+3)
    fa0 = *(const s16x8*)(buf + aoff[0][2]);
    fa1 = *(const s16x8*)(buf + aoff[0][3]);
    asm volatile("s_waitcnt lgkmcnt(0)" ::: "memory");
    __builtin_amdgcn_sched_barrier(0);
    __builtin_amdgcn_s_setprio(1);
    #pragma unroll
    for (int ni = 0; ni < 4; ++ni) acc0[2][ni] = __builtin_amdgcn_mfma_f32_16x16x32_bf16(fa0, fb[ni], acc0[2][ni], 0, 0, 0);
    #pragma unroll
    for (int ni = 0; ni < 4; ++ni) acc0[3][ni] = __builtin_amdgcn_mfma_f32_16x16x32_bf16(fa1, fb[ni], acc0[3][ni], 0, 0, 0);
    __builtin_amdgcn_s_setprio(0);
    // ---- phase 2: band1 rows 0-31 ----
    if (kt + 3 < 32) GL_B0(kt+3)
    fa0 = *(const s16x8*)(buf + aoff[1][0]);
    fa1 = *(const s16x8*)(buf + aoff[1][1]);
    asm volatile("s_waitcnt lgkmcnt(0)" ::: "memory");
    __builtin_amdgcn_sched_barrier(0);
    __builtin_amdgcn_s_setprio(1);
    #pragma unroll
    for (int ni = 0; ni < 4; ++ni) acc1[0][ni] = __builtin_amdgcn_mfma_f32_16x16x32_bf16(fa0, fb[ni], acc1[0][ni], 0, 0, 0);
    #pragma unroll
    for (int ni = 0; ni < 4; ++ni) acc1[1][ni] = __builtin_amdgcn_mfma_f32_16x16x32_bf16(fa1, fb[ni], acc1[1][ni], 0, 0, 0);
    __builtin_amdgcn_s_setprio(0);
    // ---- phase 3: band1 rows 32-63 ----
    if (kt + 3 < 32) GL_B1(kt+3)
    fa0 = *(const s16x8*)(buf + aoff[1][2]);
    fa1 = *(const s16x8*)(buf + aoff[1][3]);
    asm volatile("s_waitcnt lgkmcnt(0)" ::: "memory");
    __builtin_amdgcn_sched_barrier(0);
    __builtin_amdgcn_s_setprio(1);
    #pragma unroll
    for (int ni = 0; ni < 4; ++ni) acc1[2][ni] = __builtin_amdgcn_mfma_f32_16x16x32_bf16(fa0, fb[ni], acc1[2][ni], 0, 0, 0);
    #pragma unroll
    for (int ni = 0; ni < 4; ++ni) acc1[3][ni] = __builtin_amdgcn_mfma_f32_16x16x32_bf16(fa1, fb[ni], acc1[3][ni], 0, 0, 0);
    __builtin_amdgcn_s_setprio(0);
    // K-tile boundary: retire tile kt+1's loads; keep kt+2/kt+3 in flight
    if (kt <= 28)      { asm volatile("s_waitcnt vmcnt(8)" ::: "memory"); }
    else if (kt == 29) { asm volatile("s_waitcnt vmcnt(4)" ::: "memory"); }
    else if (kt == 30) { asm volatile("s_waitcnt vmcnt(0)" ::: "memory"); }
    __builtin_amdgcn_s_barrier();
  }
#undef GL_A0
#undef GL_A1
#undef GL_B0
#undef GL_B1

  if (EPI == 0) {
    const int tensor = (int)(brow0 >> 10);
    if (tensor == 2) {
      // V: write transposed vt[bh][dh][tok] via per-wave LDS transpose (ring LDS is dead)
      __syncthreads();
      u16* wlds = lds + wid*4224;                       // 64*66 u16 per wave
      const int hbase = (int)((brow0 + wn*64) & 1023);
      const int head = hbase >> 6;
      #pragma unroll
      for (int ph = 0; ph < 2; ++ph) {
        const long grow0 = arow0 + ph*128 + wm*64;      // 64 consecutive tokens, one batch
        const int b = (int)(grow0 >> 12), tok0r = (int)(grow0 & 4095);
        #pragma unroll
        for (int mi = 0; mi < 4; ++mi)
          #pragma unroll
          for (int ni = 0; ni < 4; ++ni) {
            const float bv = bias[brow0 + wn*64 + ni*16 + c];
            const f32x4 a = ph ? acc1[mi][ni] : acc0[mi][ni];
            #pragma unroll
            for (int r = 0; r < 4; ++r)
              wlds[(mi*16 + g*4 + r)*66 + ni*16 + c] = f2b(a[r] + bv);
          }
        asm volatile("s_waitcnt lgkmcnt(0)" ::: "memory");
        u16* vbase = outV + (((long)b*NH + head)*DH)*NTOK + tok0r;
        #pragma unroll
        for (int j = 0; j < 8; ++j) {
          const int d = j*8 + (lane >> 3);
          const int tk = (lane & 7)*8;
          s16x8 vv;
          #pragma unroll
          for (int s2 = 0; s2 < 8; ++s2) vv[s2] = (short)wlds[(tk + s2)*66 + d];
          *(s16x8*)(vbase + (long)d*NTOK + tk) = vv;
        }
        asm volatile("s_waitcnt lgkmcnt(0)" ::: "memory");
      }
    } else {
      u16* dst = (tensor == 0) ? outQ : outK;
      const float mul = (tensor == 0) ? 0.125f : 1.0f;
      #pragma unroll
      for (int ph = 0; ph < 2; ++ph)
        #pragma unroll
        for (int mi = 0; mi < 4; ++mi) {
          const int rowb = ph*128 + wm*64 + mi*16 + g*4;
          #pragma unroll
          for (int ni = 0; ni < 4; ++ni) {
            const long gcol = brow0 + wn*64 + ni*16 + c;
            const int c2 = (int)(gcol & 1023);
            const int head = c2 >> 6, dh = c2 & 63;
            const float bv = bias[gcol];
            const f32x4 a = ph ? acc1[mi][ni] : acc0[mi][ni];
            #pragma unroll
            for (int r = 0; r < 4; ++r) {
              const long grow = arow0 + rowb + r;
              const int b = (int)(grow >> 12), tok = (int)(grow & 4095);
              dst[(((long)b*NH + head)*NTOK + tok)*DH + dh] = f2b((a[r] + bv)*mul);
            }
          }
        }
    }
  } else {
    #pragma unroll
    for (int ph = 0; ph < 2; ++ph)
      #pragma unroll
      for (int mi = 0; mi < 4; ++mi) {
        const int rowb = ph*128 + wm*64 + mi*16 + g*4;
        #pragma unroll
        for (int ni = 0; ni < 4; ++ni) {
          const long gcol = brow0 + wn*64 + ni*16 + c;
          const float bv = bias[gcol];
          const f32x4 a = ph ? acc1[mi][ni] : acc0[mi][ni];
          #pragma unroll
          for (int r = 0; r < 4; ++r) {
            const long grow = arow0 + rowb + r;
            outF[grow*N + gcol] = a[r] + bv;
          }
        }
      }
  }
}

// ---------------- fp32 LDS 64x64 matmul helpers, 1024 threads (4 cols/thread) ----------------
#define PST 68
static __device__ __forceinline__ void mm_nn4(const float* A, const float* B, float* C, int t) {
  const int lane = t & 63, j0 = (t >> 6) << 2;
  float acc[4] = {0.f, 0.f, 0.f, 0.f};
  for (int k = 0; k < 64; k += 4) {
    const f32x4 a4 = *(const f32x4*)&A[lane*PST + k];
    #pragma unroll
    for (int dk = 0; dk < 4; ++dk) {
      const f32x4 b0 = *(const f32x4*)&B[(k + dk)*PST + j0];
      #pragma unroll
      for (int q = 0; q < 4; ++q) acc[q] += a4[dk]*b0[q];
    }
  }
  #pragma unroll
  for (int j = 0; j < 4; ++j) C[lane*PST + j0 + j] = acc[j];
}
static __device__ __forceinline__ void mm_nt4(const float* A, const float* B, float* C, int t) {
  const int lane = t & 63, j0 = (t >> 6) << 2;
  float acc[4] = {0.f, 0.f, 0.f, 0.f};
  for (int k = 0; k < 64; k += 4) {
    const f32x4 a4 = *(const f32x4*)&A[lane*PST + k];
    #pragma unroll
    for (int jj = 0; jj < 4; ++jj) {
      const f32x4 b4 = *(const f32x4*)&B[(j0 + jj)*PST + k];
      acc[jj] += a4[0]*b4[0] + a4[1]*b4[1] + a4[2]*b4[2] + a4[3]*b4[3];
    }
  }
  #pragma unroll
  for (int j = 0; j < 4; ++j) C[lane*PST + j0 + j] = acc[j];
}

// ---------------- sim2 + softmax + Newton-Schulz pinv (all fp32, 1024 thr) ----------------
__global__ __launch_bounds__(1024) void k_pinv(const float* __restrict__ qlf, const float* __restrict__ klf,
                                               float* __restrict__ a2inv) {
  __shared__ __align__(16) float Xb[64*PST];
  __shared__ __align__(16) float Vb[64*PST];
  __shared__ __align__(16) float T1[64*PST];
  __shared__ __align__(16) float T2[64*PST];
  __shared__ __align__(16) float T3[64*PST];
  const int bh = blockIdx.x, t = threadIdx.x;
  const float* ql = qlf + (long)bh*4096;
  const float* kl = klf + (long)bh*4096;
  for (int i = t; i < 4096; i += 1024) { T1[(i>>6)*PST + (i&63)] = ql[i]; T2[(i>>6)*PST + (i&63)] = kl[i]; }
  __syncthreads();
  mm_nt4(T1, T2, Xb, t);          // sim2 = q_l @ k_l^T
  __syncthreads();
  if (t < 64) {                   // row softmax (precise exp on the chaotic path)
    float mx = -1e30f;
    for (int j = 0; j < 64; ++j) mx = fmaxf(mx, Xb[t*PST + j]);
    float s = 0.f;
    for (int j = 0; j < 64; ++j) { const float e = expf(Xb[t*PST + j] - mx); Xb[t*PST + j] = e; s += e; }
    const float inv = 1.0f/s;
    for (int j = 0; j < 64; ++j) Xb[t*PST + j] *= inv;
  }
  __syncthreads();
  for (int i = t; i < 4096; i += 1024) { const int r = i>>6, cc = i&63; Vb[r*PST+cc] = Xb[r*PST+cc]; }
  __syncthreads();
  for (int it = 0; it < 6; ++it) {
    mm_nn4(Xb, Vb, T1, t);  __syncthreads();
    for (int i = t; i < 4096; i += 1024) { const int r=i>>6, cc=i&63; T2[r*PST+cc] = (r==cc?7.0f:0.0f) - T1[r*PST+cc]; }
    __syncthreads();
    mm_nn4(T1, T2, T3, t);  __syncthreads();
    for (int i = t; i < 4096; i += 1024) { const int r=i>>6, cc=i&63; T2[r*PST+cc] = (r==cc?15.0f:0.0f) - T3[r*PST+cc]; }
    __syncthreads();
    mm_nn4(T1, T2, T3, t);  __syncthreads();
    for (int i = t; i < 4096; i += 1024) { const int r=i>>6, cc=i&63; T2[r*PST+cc] = (r==cc?13.0f:0.0f) - T3[r*PST+cc]; }
    __syncthreads();
    mm_nn4(Vb, T2, T3, t);  __syncthreads();
    for (int i = t; i < 4096; i += 1024) { const int r=i>>6, cc=i&63; Vb[r*PST+cc] = 0.25f*T3[r*PST+cc]; }
    __syncthreads();
  }
  for (int i = t; i < 4096; i += 1024) a2inv[(long)bh*4096 + i] = Vb[(i>>6)*PST + (i&63)];
}

// ---------------- attn3 @ v partials: 8 blocks per (b,h), 512 tokens each ----------------
__global__ __launch_bounds__(256) void k_attn3v_p(const u16* __restrict__ qlb, const u16* __restrict__ kk,
                                                  const u16* __restrict__ vt,
                                                  float* __restrict__ zp, float* __restrict__ sp) {
  __shared__ __align__(16) float Zl[4][64][64];
  __shared__ float Sl[4][64];
  __shared__ __align__(16) u16 Pl[4][64][40];
  const int bh = blockIdx.x >> 3, qt = blockIdx.x & 7;
  const int t = threadIdx.x, w = t >> 6, lane = t & 63;
  const int c = lane & 15, g = lane >> 4;

  s16x8 aq[4][2];
  const u16* qlp = qlb + (long)bh*4096;
  #pragma unroll
  for (int mi = 0; mi < 4; ++mi)
    #pragma unroll
    for (int ks = 0; ks < 2; ++ks)
      aq[mi][ks] = ld8(qlp + (mi*16 + c)*64 + ks*32 + g*8);

  f32x4 zacc[4][4] = {};
  float sl[4][4] = {};
  const u16* kp = kk + (long)bh*NTOK*DH;
  const u16* vp = vt + (long)bh*DH*NTOK;
  char* pbase = (char*)&Pl[w][0][0];
  const int tok00 = qt*512 + w*128;

  for (int it = 0; it < 4; ++it) {
    const int t0 = tok00 + it*32;
    f32x4 sacc[4][2] = {};
    s16x8 kb[2][2];
    #pragma unroll
    for (int cg = 0; cg < 2; ++cg)
      #pragma unroll
      for (int ks = 0; ks < 2; ++ks)
        kb[cg][ks] = ld8(kp + (long)(t0 + cg*16 + c)*64 + ks*32 + g*8);
    #pragma unroll
    for (int cg = 0; cg < 2; ++cg)
      #pragma unroll
      for (int ks = 0; ks < 2; ++ks)
        #pragma unroll
        for (int mi = 0; mi < 4; ++mi)
          sacc[mi][cg] = __builtin_amdgcn_mfma_f32_16x16x32_bf16(aq[mi][ks], kb[cg][ks], sacc[mi][cg], 0, 0, 0);
    #pragma unroll
    for (int mi = 0; mi < 4; ++mi)
      #pragma unroll
      for (int r = 0; r < 4; ++r) {
        const int row = mi*16 + g*4 + r;
        const float p0 = __expf(sacc[mi][0][r]);
        const float p1 = __expf(sacc[mi][1][r]);
        sl[mi][r] += p0 + p1;
        char* base = pbase + row*80;
        *(u16*)(base + c*2)      = f2b(p0);
        *(u16*)(base + 32 + c*2) = f2b(p1);
      }
    s16x8 pa[4];
    #pragma unroll
    for (int mi = 0; mi < 4; ++mi) pa[mi] = *(const s16x8*)(pbase + (mi*16 + c)*80 + g*16);
    #pragma unroll
    for (int ni = 0; ni < 4; ++ni) {
      const s16x8 vb = ld8(vp + (long)(ni*16 + c)*NTOK + t0 + g*8);
      #pragma unroll
      for (int mi = 0; mi < 4; ++mi)
        zacc[mi][ni] = __builtin_amdgcn_mfma_f32_16x16x32_bf16(pa[mi], vb, zacc[mi][ni], 0, 0, 0);
    }
  }
  #pragma unroll
  for (int mi = 0; mi < 4; ++mi)
    #pragma unroll
    for (int r = 0; r < 4; ++r) {
      float s = sl[mi][r];
      s += __shfl_xor(s, 1); s += __shfl_xor(s, 2); s += __shfl_xor(s, 4); s += __shfl_xor(s, 8);
      sl[mi][r] = s;
    }
  #pragma unroll
  for (int mi = 0; mi < 4; ++mi)
    #pragma unroll
    for (int ni = 0; ni < 4; ++ni)
      #pragma unroll
      for (int r = 0; r < 4; ++r)
        Zl[w][mi*16 + g*4 + r][ni*16 + c] = zacc[mi][ni][r];
  if (c == 0)
    #pragma unroll
    for (int mi = 0; mi < 4; ++mi)
      #pragma unroll
      for (int r = 0; r < 4; ++r)
        Sl[w][mi*16 + g*4 + r] = sl[mi][r];
  __syncthreads();
  float* zpp = zp + (long)blockIdx.x*4096;
  for (int i = t; i < 4096; i += 256) {
    const int row = i >> 6, dh = i & 63;
    zpp[i] = Zl[0][row][dh] + Zl[1][row][dh] + Zl[2][row][dh] + Zl[3][row][dh];
  }
  if (t < 64) sp[(long)blockIdx.x*64 + t] = Sl[0][t] + Sl[1][t] + Sl[2][t] + Sl[3][t];
}

// ---------------- fused: z-reduce + W2^T = (attn2inv @ z)^T  (bf16 [dh][lm], 1024 thr) ----------------
__global__ __launch_bounds__(1024) void k_w2(const float* __restrict__ a2inv,
                                             const float* __restrict__ zp, const float* __restrict__ sp,
                                             u16* __restrict__ w2t) {
  __shared__ __align__(16) float Ai[64*PST];
  __shared__ __align__(16) float Zi[64*PST];
  __shared__ __align__(16) float Ci[64*PST];
  __shared__ float Ss[64];
  const int bh = blockIdx.x, t = threadIdx.x;
  if (t < 64) {
    float ss = 0.f;
    #pragma unroll
    for (int qt = 0; qt < 8; ++qt) ss += sp[(long)(bh*8 + qt)*64 + t];
    Ss[t] = 1.0f / ss;
  }
  for (int i = t; i < 4096; i += 1024)
    Ai[(i>>6)*PST + (i&63)] = a2inv[(long)bh*4096 + i];
  __syncthreads();
  for (int i = t; i < 4096; i += 1024) {
    float zs = 0.f;
    #pragma unroll
    for (int qt = 0; qt < 8; ++qt) zs += zp[((long)(bh*8 + qt))*4096 + i];
    Zi[(i>>6)*PST + (i&63)] = zs * Ss[i>>6];
  }
  __syncthreads();
  mm_nn4(Ai, Zi, Ci, t);
  __syncthreads();
  for (int i = t; i < 4096; i += 1024) { const int r = i>>6, cc = i&63; w2t[(long)bh*4096 + cc*64 + r] = f2b(Ci[r*PST + cc]); }
}

// ---------------- out_h = softmax(q @ k_l^T) @ W2, fused, writes attnout bf16 ----------------
#define P1ST 144
__global__ __launch_bounds__(256) void k_attn1(const u16* __restrict__ q, const u16* __restrict__ klb,
                                               const u16* __restrict__ w2t, u16* __restrict__ ao) {
  __shared__ __align__(16) u16 Pl[4][64][72];
  const int bx = blockIdx.x, bh = bx >> 4, tt = bx & 15;
  const int b = bh >> 4, h = bh & 15;
  const int t = threadIdx.x, w = t >> 6, lane = t & 63;
  const int c = lane & 15, g = lane >> 4;
  const int tok0 = tt*256 + w*64;
  const u16* qp  = q + ((long)bh*NTOK + tok0)*DH;
  const u16* klp = klb + (long)bh*4096;
  const u16* wp  = w2t + (long)bh*4096;
  char* pbase = (char*)&Pl[w][0][0];

  s16x8 aq[4][2], kb[4][2], wb[4][2];
  #pragma unroll
  for (int i = 0; i < 4; ++i)
    #pragma unroll
    for (int ks = 0; ks < 2; ++ks) {
      aq[i][ks] = ld8(qp + (long)(i*16 + c)*DH + ks*32 + g*8);
      kb[i][ks] = ld8(klp + (i*16 + c)*64 + ks*32 + g*8);
      wb[i][ks] = ld8(wp  + (i*16 + c)*64 + ks*32 + g*8);
    }
  f32x4 sacc[4][4] = {};
  #pragma unroll
  for (int ks = 0; ks < 2; ++ks)
    #pragma unroll
    for (int mi = 0; mi < 4; ++mi)
      #pragma unroll
      for (int ni = 0; ni < 4; ++ni)
        sacc[mi][ni] = __builtin_amdgcn_mfma_f32_16x16x32_bf16(aq[mi][ks], kb[ni][ks], sacc[mi][ni], 0, 0, 0);

  float rs[4][4];
  #pragma unroll
  for (int mi = 0; mi < 4; ++mi)
    #pragma unroll
    for (int r = 0; r < 4; ++r) {
      const int row = mi*16 + g*4 + r;
      char* base = pbase + row*P1ST;
      float ssum = 0.f;
      #pragma unroll
      for (int ni = 0; ni < 4; ++ni) {
        const float p = __expf(sacc[mi][ni][r]);
        ssum += p;
        *(u16*)(base + (ni*16 + c)*2) = f2b(p);
      }
      ssum += __shfl_xor(ssum, 1); ssum += __shfl_xor(ssum, 2);
      ssum += __shfl_xor(ssum, 4); ssum += __shfl_xor(ssum, 8);
      rs[mi][r] = ssum;
    }
  __builtin_amdgcn_s_barrier();
  s16x8 pa[4][2];
  #pragma unroll
  for (int mi = 0; mi < 4; ++mi)
    #pragma unroll
    for (int ks = 0; ks < 2; ++ks)
      pa[mi][ks] = *(const s16x8*)(pbase + (mi*16 + c)*P1ST + ks*64 + g*16);
  f32x4 oacc[4][4] = {};
  #pragma unroll
  for (int ks = 0; ks < 2; ++ks)
    #pragma unroll
    for (int mi = 0; mi < 4; ++mi)
      #pragma unroll
      for (int ni = 0; ni < 4; ++ni)
        oacc[mi][ni] = __builtin_amdgcn_mfma_f32_16x16x32_bf16(pa[mi][ks], wb[ni][ks], oacc[mi][ni], 0, 0, 0);

  u16* op = ao + (long)b*NTOK*DM + (long)h*64;
  #pragma unroll
  for (int mi = 0; mi < 4; ++mi)
    #pragma unroll
    for (int r = 0; r < 4; ++r) {
      const int tok = tok0 + mi*16 + g*4 + r;
      const float inv = 1.0f / rs[mi][r];
      #pragma unroll
      for (int ni = 0; ni < 4; ++ni)
        op[(long)tok*DM + ni*16 + c] = f2b(oacc[mi][ni][r] * inv);
    }
}

extern "C" void kernel_launch(void* const* d_in, const int* in_sizes, int n_in,
                              void* d_out, int out_size, void* d_ws, size_t ws_size,
                              hipStream_t stream) {
  const float* hs   = (const float*)d_in[0];
  const float* Wqkv = (const float*)d_in[1];
  const float* bqkv = (const float*)d_in[2];
  const float* Wout = (const float*)d_in[3];
  const float* bout = (const float*)d_in[4];
  float* out = (float*)d_out;
  char* w = (char*)d_ws;

  u16*  Xb    = (u16*)(w);                 // 32MB; free after QKV gemm
  float* zp   = (float*)(w);               // aliases Xb: written by attn3v_p (after gemm0), 8MB
  float* sp   = (float*)(w + 8388608L);    // within Xb region
  u16*  WqkvT = (u16*)(w + 33554432L);
  u16*  WoutT = (u16*)(w + 39845888L);
  u16*  q     = (u16*)(w + 41943040L);
  float* psum = (float*)(w + 41943040L);   // aliases q: consumed by k_lreduce before gemm writes q
  u16*  k     = (u16*)(w + 75497472L);
  u16*  vt    = (u16*)(w + 142606336L);    // written directly by gemm0's V epilogue
  float* Xl   = (float*)(w + 109051904L);  // old v slot (unused otherwise)
  float* qlf  = (float*)(w + 176160768L);
  float* klf  = (float*)(w + 177209344L);
  u16*  qlb   = (u16*)(w + 178257920L);
  u16*  klb   = (u16*)(w + 178782208L);
  float* a2i  = (float*)(w + 179306496L);
  u16*  w2t   = (u16*)(w + 181403648L);
  u16*  ao    = (u16*)(w + 181927936L);

  k_cvt_xl<<<dim3(256,4), 256, 0, stream>>>(hs, Xb, Xl);
  k_cvt_t<<<dim3(48,16), 256, 0, stream>>>(Wqkv, WqkvT, 1024, 3072);
  k_cvt_t<<<dim3(16,16), 256, 0, stream>>>(Wout, WoutT, 1024, 1024);
  k_lproj2<<<dim3(8,8,8), 256, 0, stream>>>(Xl, Wqkv, psum);
  k_lreduce<<<2048, 256, 0, stream>>>(psum, bqkv, qlf, klf, qlb, klb);
  k_gemm256<0><<<dim3(64,12), 512, 0, stream>>>(Xb, WqkvT, bqkv, 3072, nullptr, q, k, vt);
  k_pinv<<<64, 1024, 0, stream>>>(qlf, klf, a2i);
  k_attn3v_p<<<512, 256, 0, stream>>>(qlb, k, vt, zp, sp);
  k_w2<<<64, 1024, 0, stream>>>(a2i, zp, sp, w2t);
  k_attn1<<<1024, 256, 0, stream>>>(q, klb, w2t, ao);
  k_gemm256<1><<<dim3(64,4), 512, 0, stream>>>(ao, WoutT, bout, 1024, out, nullptr, nullptr, nullptr);
}

// Round 11
// 334.628 us; speedup vs baseline: 5.8203x; 1.0655x over previous
//
#include <hip/hip_runtime.h>
#include <cstdint>

typedef unsigned short u16;
typedef __attribute__((ext_vector_type(8))) short s16x8;
typedef __attribute__((ext_vector_type(4))) float f32x4;

#define NTOK 4096
#define DH   64
#define DM   1024
#define NH   16

static __device__ __forceinline__ float b2f(u16 u){ return __uint_as_float(((unsigned)u)<<16); }
static __device__ __forceinline__ u16 f2b(float f){
  unsigned u = __float_as_uint(f);
  return (u16)((u + 0x7FFFu + ((u>>16)&1u)) >> 16);   // RNE
}

static __device__ __forceinline__ void gload_lds16(const void* g, void* l) {
  __builtin_amdgcn_global_load_lds(
      (const __attribute__((address_space(1))) unsigned*)(uintptr_t)g,
      (__attribute__((address_space(3))) unsigned*)(uintptr_t)l, 16, 0, 0);
}

static __device__ __forceinline__ s16x8 ld8(const u16* p){ return *(const s16x8*)(const void*)p; }

// ---------------- merged pre-pass: cvt_xl (1024 blks) | cvt_t Wqkv (768) | cvt_t Wout (256) ----------------
__global__ __launch_bounds__(256) void k_pre(const float* __restrict__ hs, u16* __restrict__ Xb,
                                             float* __restrict__ Xl,
                                             const float* __restrict__ Wqkv, u16* __restrict__ WqkvT,
                                             const float* __restrict__ Wout, u16* __restrict__ WoutT) {
  __shared__ float tile[64][65];
  const int bid = blockIdx.x, t = threadIdx.x;
  if (bid < 1024) {
    // cvt_xl: grp = bid>>2, d-chunk = bid&3
    const int grp = bid >> 2;
    const int d = (bid & 3)*256 + t;
    const float* p = hs + (long)grp*64*DM + d;
    u16* xo = Xb + (long)grp*64*DM + d;
    float s = 0.f;
    #pragma unroll 8
    for (int i = 0; i < 64; ++i) {
      const float v = p[(long)i*DM];
      s += v;
      xo[(long)i*DM] = f2b(v);
    }
    Xl[(long)grp*DM + d] = s * (1.0f/64.0f);
    return;
  }
  // cvt_t branches
  const float* in; u16* out; int R, C, tc, tr;
  if (bid < 1792) { const int x = bid - 1024; in = Wqkv; out = WqkvT; R = 1024; C = 3072; tc = x % 48; tr = x / 48; }
  else            { const int x = bid - 1792; in = Wout; out = WoutT; R = 1024; C = 1024; tc = x & 15;  tr = x >> 4; }
  const int cx = t & 63, ry = t >> 6;
  #pragma unroll
  for (int p = 0; p < 16; ++p) {
    const int row = p*4 + ry;
    tile[row][cx] = in[(long)(tr*64 + row)*C + tc*64 + cx];
  }
  __syncthreads();
  #pragma unroll
  for (int p = 0; p < 16; ++p) {
    const int orow = p*4 + ry;
    out[(long)(tc*64 + orow)*R + tr*64 + cx] = f2b(tile[cx][orow]);
  }
}

// ---------------- fp32 projection, K-split: psum[z][row][col] partials ----------------
__global__ __launch_bounds__(256) void k_lproj2(const float* __restrict__ Xl, const float* __restrict__ Wqkv,
                                                float* __restrict__ psum) {
  __shared__ __align__(16) float Xs[32][68];
  const int t = threadIdx.x;
  const int wcol = blockIdx.x*256 + t;    // 0..2047
  const int r0 = blockIdx.y*32;
  const int kbase = blockIdx.z*128;
  float acc[32];
  #pragma unroll
  for (int r = 0; r < 32; ++r) acc[r] = 0.f;
  for (int k0 = kbase; k0 < kbase + 128; k0 += 64) {
    __syncthreads();
    for (int idx = t; idx < 2048; idx += 256)
      Xs[idx>>6][idx&63] = Xl[(long)(r0 + (idx>>6))*DM + k0 + (idx&63)];
    __syncthreads();
    for (int kk = 0; kk < 64; kk += 4) {
      f32x4 wv;
      #pragma unroll
      for (int j = 0; j < 4; ++j) wv[j] = Wqkv[(long)(k0+kk+j)*3072 + wcol];
      #pragma unroll
      for (int r = 0; r < 32; ++r) {
        const f32x4 xv = *(const f32x4*)&Xs[r][kk];
        acc[r] += xv[0]*wv[0] + xv[1]*wv[1] + xv[2]*wv[2] + xv[3]*wv[3];
      }
    }
  }
  float* po = psum + ((long)blockIdx.z*256 + r0)*2048 + wcol;
  #pragma unroll
  for (int r = 0; r < 32; ++r) po[(long)r*2048] = acc[r];
}

// ---------------- reduce K-slices + bias + scale -> qlf/klf/qlb/klb ----------------
__global__ __launch_bounds__(256) void k_lreduce(const float* __restrict__ psum, const float* __restrict__ bqkv,
                                                 float* __restrict__ qlf, float* __restrict__ klf,
                                                 u16* __restrict__ qlb, u16* __restrict__ klb) {
  const long idx = (long)blockIdx.x*256 + threadIdx.x;
  const int row = (int)(idx >> 11), col = (int)(idx & 2047);
  float s = 0.f;
  #pragma unroll
  for (int z = 0; z < 8; ++z) s += psum[((long)z*256 + row)*2048 + col];
  const int isq = (col < 1024) ? 1 : 0;
  float val = s + bqkv[col];
  if (isq) val *= 0.125f;
  const int b = row >> 6, lm = row & 63;
  const int c2 = col & 1023, h = c2 >> 6, dh = c2 & 63;
  const long o = (((long)b*NH + h)*64 + lm)*64 + dh;
  if (isq) { qlf[o] = val; qlb[o] = f2b(val); }
  else     { klf[o] = val; klb[o] = f2b(val); }
}

// ---------------- GEMM 256x256, BK=32, 8 waves, 4-deep LDS ring, counted vmcnt (r6 core) ----------------
// r11: r6 inner schedule restored (best measured: 109us, MfmaUtil 41%); V-transpose epilogue kept.
// Ledger: stage kt+3 at tile top; vmcnt(8/4/0)+barrier at tile end; nf/nb register prefetch.
// LDS swizzle (r5-verified, 0 conflicts): source chunk ^ (row>>1)&3, read offset g ^ (c>>1)&3.
template<int EPI>
__global__ __launch_bounds__(512, 2) void k_gemm256(
    const u16* __restrict__ A, const u16* __restrict__ Bt, const float* __restrict__ bias,
    int N, float* __restrict__ outF, u16* __restrict__ outQ, u16* __restrict__ outK, u16* __restrict__ outV)
{
  __shared__ __align__(16) u16 lds[4*16384];
  const int K = 1024;
  const int t = threadIdx.x;
  const int lane = t & 63;
  const int wid = t >> 6;
  const int c = lane & 15, g = lane >> 4;
  const int wm = wid >> 2, wn = wid & 3;
  const int fid = blockIdx.y*64 + blockIdx.x;
  const int nbx = ((fid & 7) << 3) | ((fid >> 3) & 7);
  const int nby = fid >> 6;
  const long arow0 = (long)nbx * 256;
  const long brow0 = (long)nby * 256;
  char* ldsb = (char*)lds;

  const int srow = t >> 2;
  const int schunk = (t & 3) ^ ((srow >> 1) & 3);
  const u16* gA0 = A  + (arow0 + srow)*K       + schunk*8;
  const u16* gA1 = A  + (arow0 + 128 + srow)*K + schunk*8;
  const u16* gB0 = Bt + (brow0 + srow)*K       + schunk*8;
  const u16* gB1 = Bt + (brow0 + 128 + srow)*K + schunk*8;
  const int dstoff = t*16;

#define STAGE_A(kt) { char* bse = ldsb + ((kt)&3)*32768; \
    gload_lds16(gA0 + (kt)*32, bse + dstoff); \
    gload_lds16(gA1 + (kt)*32, bse + 8192 + dstoff); }
#define STAGE_B(kt) { char* bse = ldsb + ((kt)&3)*32768 + 16384; \
    gload_lds16(gB0 + (kt)*32, bse + dstoff); \
    gload_lds16(gB1 + (kt)*32, bse + 8192 + dstoff); }

  const int gs = g ^ ((c >> 1) & 3);
  int aoff[2][4], boff[4];
  #pragma unroll
  for (int mi = 0; mi < 4; ++mi) {
    aoff[0][mi] = (0*128 + wm*64 + mi*16 + c)*64 + gs*16;
    aoff[1][mi] = (1*128 + wm*64 + mi*16 + c)*64 + gs*16;
    boff[mi]    = 16384 + (wn*64 + mi*16 + c)*64 + gs*16;
  }

  f32x4 acc0[4][4] = {};
  f32x4 acc1[4][4] = {};

  STAGE_A(0); STAGE_B(0); STAGE_A(1); STAGE_B(1); STAGE_A(2); STAGE_B(2);
  asm volatile("s_waitcnt vmcnt(8)" ::: "memory");
  __builtin_amdgcn_s_barrier();

  s16x8 af[4], bfr[4], af2[4];
  #pragma unroll
  for (int mi = 0; mi < 4; ++mi) af[mi]  = *(const s16x8*)(ldsb + aoff[0][mi]);
  #pragma unroll
  for (int ni = 0; ni < 4; ++ni) bfr[ni] = *(const s16x8*)(ldsb + boff[ni]);

  for (int kt = 0; kt < 32; ++kt) {
    char* buf  = ldsb + (kt&3)*32768;
    char* bufn = ldsb + ((kt+1)&3)*32768;
    if (kt + 3 < 32) { STAGE_A(kt+3) STAGE_B(kt+3) }
    asm volatile("s_waitcnt lgkmcnt(0)" ::: "memory");
    __builtin_amdgcn_sched_barrier(0);
    #pragma unroll
    for (int mi = 0; mi < 4; ++mi) af2[mi] = *(const s16x8*)(buf + aoff[1][mi]);
    __builtin_amdgcn_sched_barrier(0);
    __builtin_amdgcn_s_setprio(1);
    #pragma unroll
    for (int mi = 0; mi < 4; ++mi)
      #pragma unroll
      for (int ni = 0; ni < 4; ++ni)
        acc0[mi][ni] = __builtin_amdgcn_mfma_f32_16x16x32_bf16(af[mi], bfr[ni], acc0[mi][ni], 0, 0, 0);
    __builtin_amdgcn_s_setprio(0);
    asm volatile("s_waitcnt lgkmcnt(0)" ::: "memory");
    __builtin_amdgcn_sched_barrier(0);
    if (kt <= 28)      { asm volatile("s_waitcnt vmcnt(8)" ::: "memory"); }
    else if (kt == 29) { asm volatile("s_waitcnt vmcnt(4)" ::: "memory"); }
    else if (kt == 30) { asm volatile("s_waitcnt vmcnt(0)" ::: "memory"); }
    if (kt < 31) __builtin_amdgcn_s_barrier();
    s16x8 nf[4], nb[4];
    if (kt < 31) {
      #pragma unroll
      for (int mi = 0; mi < 4; ++mi) nf[mi] = *(const s16x8*)(bufn + aoff[0][mi]);
      #pragma unroll
      for (int ni = 0; ni < 4; ++ni) nb[ni] = *(const s16x8*)(bufn + boff[ni]);
    }
    __builtin_amdgcn_sched_barrier(0);
    __builtin_amdgcn_s_setprio(1);
    #pragma unroll
    for (int mi = 0; mi < 4; ++mi)
      #pragma unroll
      for (int ni = 0; ni < 4; ++ni)
        acc1[mi][ni] = __builtin_amdgcn_mfma_f32_16x16x32_bf16(af2[mi], bfr[ni], acc1[mi][ni], 0, 0, 0);
    __builtin_amdgcn_s_setprio(0);
    if (kt < 31) {
      #pragma unroll
      for (int mi = 0; mi < 4; ++mi) { af[mi] = nf[mi]; bfr[mi] = nb[mi]; }
    }
  }
#undef STAGE_A
#undef STAGE_B

  if (EPI == 0) {
    const int tensor = (int)(brow0 >> 10);
    if (tensor == 2) {
      // V: write transposed vt[bh][dh][tok] via per-wave LDS transpose (ring LDS dead)
      __syncthreads();
      u16* wlds = lds + wid*4224;                       // 64*66 u16 per wave
      const int hbase = (int)((brow0 + wn*64) & 1023);
      const int head = hbase >> 6;
      #pragma unroll
      for (int ph = 0; ph < 2; ++ph) {
        const long grow0 = arow0 + ph*128 + wm*64;
        const int b = (int)(grow0 >> 12), tok0r = (int)(grow0 & 4095);
        #pragma unroll
        for (int mi = 0; mi < 4; ++mi)
          #pragma unroll
          for (int ni = 0; ni < 4; ++ni) {
            const float bv = bias[brow0 + wn*64 + ni*16 + c];
            const f32x4 a = ph ? acc1[mi][ni] : acc0[mi][ni];
            #pragma unroll
            for (int r = 0; r < 4; ++r)
              wlds[(mi*16 + g*4 + r)*66 + ni*16 + c] = f2b(a[r] + bv);
          }
        asm volatile("s_waitcnt lgkmcnt(0)" ::: "memory");
        u16* vbase = outV + (((long)b*NH + head)*DH)*NTOK + tok0r;
        #pragma unroll
        for (int j = 0; j < 8; ++j) {
          const int d = j*8 + (lane >> 3);
          const int tk = (lane & 7)*8;
          s16x8 vv;
          #pragma unroll
          for (int s2 = 0; s2 < 8; ++s2) vv[s2] = (short)wlds[(tk + s2)*66 + d];
          *(s16x8*)(vbase + (long)d*NTOK + tk) = vv;
        }
        asm volatile("s_waitcnt lgkmcnt(0)" ::: "memory");
      }
    } else {
      u16* dst = (tensor == 0) ? outQ : outK;
      const float mul = (tensor == 0) ? 0.125f : 1.0f;
      #pragma unroll
      for (int ph = 0; ph < 2; ++ph)
        #pragma unroll
        for (int mi = 0; mi < 4; ++mi) {
          const int rowb = ph*128 + wm*64 + mi*16 + g*4;
          #pragma unroll
          for (int ni = 0; ni < 4; ++ni) {
            const long gcol = brow0 + wn*64 + ni*16 + c;
            const int c2 = (int)(gcol & 1023);
            const int head = c2 >> 6, dh = c2 & 63;
            const float bv = bias[gcol];
            const f32x4 a = ph ? acc1[mi][ni] : acc0[mi][ni];
            #pragma unroll
            for (int r = 0; r < 4; ++r) {
              const long grow = arow0 + rowb + r;
              const int b = (int)(grow >> 12), tok = (int)(grow & 4095);
              dst[(((long)b*NH + head)*NTOK + tok)*DH + dh] = f2b((a[r] + bv)*mul);
            }
          }
        }
    }
  } else {
    #pragma unroll
    for (int ph = 0; ph < 2; ++ph)
      #pragma unroll
      for (int mi = 0; mi < 4; ++mi) {
        const int rowb = ph*128 + wm*64 + mi*16 + g*4;
        #pragma unroll
        for (int ni = 0; ni < 4; ++ni) {
          const long gcol = brow0 + wn*64 + ni*16 + c;
          const float bv = bias[gcol];
          const f32x4 a = ph ? acc1[mi][ni] : acc0[mi][ni];
          #pragma unroll
          for (int r = 0; r < 4; ++r) {
            const long grow = arow0 + rowb + r;
            outF[grow*N + gcol] = a[r] + bv;
          }
        }
      }
  }
}

// ---------------- fp32 LDS 64x64 matmul helpers ----------------
#define PST 68
static __device__ __forceinline__ void mm_nn8(const float* A, const float* B, float* C, int t) {
  const int lane = t & 63, j0 = (t >> 6) << 3;
  float acc[8];
  #pragma unroll
  for (int j = 0; j < 8; ++j) acc[j] = 0.f;
  for (int k = 0; k < 64; k += 4) {
    const f32x4 a4 = *(const f32x4*)&A[lane*PST + k];
    #pragma unroll
    for (int dk = 0; dk < 4; ++dk) {
      const float a = a4[dk];
      const float* br = &B[(k + dk)*PST + j0];
      const f32x4 b0 = *(const f32x4*)(br);
      const f32x4 b1 = *(const f32x4*)(br + 4);
      #pragma unroll
      for (int qq = 0; qq < 4; ++qq) { acc[qq] += a*b0[qq]; acc[4+qq] += a*b1[qq]; }
    }
  }
  #pragma unroll
  for (int j = 0; j < 8; ++j) C[lane*PST + j0 + j] = acc[j];
}
static __device__ __forceinline__ void mm_nt8(const float* A, const float* B, float* C, int t) {
  const int lane = t & 63, j0 = (t >> 6) << 3;
  float acc[8];
  #pragma unroll
  for (int j = 0; j < 8; ++j) acc[j] = 0.f;
  for (int k = 0; k < 64; k += 4) {
    const f32x4 a4 = *(const f32x4*)&A[lane*PST + k];
    #pragma unroll
    for (int jj = 0; jj < 8; ++jj) {
      const f32x4 b4 = *(const f32x4*)&B[(j0 + jj)*PST + k];
      acc[jj] += a4[0]*b4[0] + a4[1]*b4[1] + a4[2]*b4[2] + a4[3]*b4[3];
    }
  }
  #pragma unroll
  for (int j = 0; j < 8; ++j) C[lane*PST + j0 + j] = acc[j];
}
static __device__ __forceinline__ void mm_nn4(const float* A, const float* B, float* C, int t) {
  const int lane = t & 63, j0 = (t >> 6) << 2;
  float acc[4] = {0.f, 0.f, 0.f, 0.f};
  for (int k = 0; k < 64; k += 4) {
    const f32x4 a4 = *(const f32x4*)&A[lane*PST + k];
    #pragma unroll
    for (int dk = 0; dk < 4; ++dk) {
      const f32x4 b0 = *(const f32x4*)&B[(k + dk)*PST + j0];
      #pragma unroll
      for (int q = 0; q < 4; ++q) acc[q] += a4[dk]*b0[q];
    }
  }
  #pragma unroll
  for (int j = 0; j < 4; ++j) C[lane*PST + j0 + j] = acc[j];
}

// ---------------- merged: pinv (blocks 0..63) | attn3v partials (blocks 64..575) ----------------
// pinv uses all 512 threads (mm_nn8); attn3v computes with t<256, all threads join the barrier.
__global__ __launch_bounds__(512) void k_pa(const float* __restrict__ qlf, const float* __restrict__ klf,
                                            float* __restrict__ a2inv,
                                            const u16* __restrict__ qlb, const u16* __restrict__ kk,
                                            const u16* __restrict__ vt,
                                            float* __restrict__ zp, float* __restrict__ sp) {
  __shared__ __align__(16) char smem[87040];
  const int t = threadIdx.x;
  if (blockIdx.x < 64) {
    // ---- pinv: sim2 + softmax + Newton-Schulz (fp32) ----
    float* Xb = (float*)smem;
    float* Vb = Xb + 64*PST;
    float* T1 = Vb + 64*PST;
    float* T2 = T1 + 64*PST;
    float* T3 = T2 + 64*PST;
    const int bh = blockIdx.x;
    const float* ql = qlf + (long)bh*4096;
    const float* kl = klf + (long)bh*4096;
    for (int i = t; i < 4096; i += 512) { T1[(i>>6)*PST + (i&63)] = ql[i]; T2[(i>>6)*PST + (i&63)] = kl[i]; }
    __syncthreads();
    mm_nt8(T1, T2, Xb, t);
    __syncthreads();
    if (t < 64) {
      float mx = -1e30f;
      for (int j = 0; j < 64; ++j) mx = fmaxf(mx, Xb[t*PST + j]);
      float s = 0.f;
      for (int j = 0; j < 64; ++j) { const float e = expf(Xb[t*PST + j] - mx); Xb[t*PST + j] = e; s += e; }
      const float inv = 1.0f/s;
      for (int j = 0; j < 64; ++j) Xb[t*PST + j] *= inv;
    }
    __syncthreads();
    for (int i = t; i < 4096; i += 512) { const int r = i>>6, cc = i&63; Vb[r*PST+cc] = Xb[r*PST+cc]; }
    __syncthreads();
    for (int it = 0; it < 6; ++it) {
      mm_nn8(Xb, Vb, T1, t);  __syncthreads();
      for (int i = t; i < 4096; i += 512) { const int r=i>>6, cc=i&63; T2[r*PST+cc] = (r==cc?7.0f:0.0f) - T1[r*PST+cc]; }
      __syncthreads();
      mm_nn8(T1, T2, T3, t);  __syncthreads();
      for (int i = t; i < 4096; i += 512) { const int r=i>>6, cc=i&63; T2[r*PST+cc] = (r==cc?15.0f:0.0f) - T3[r*PST+cc]; }
      __syncthreads();
      mm_nn8(T1, T2, T3, t);  __syncthreads();
      for (int i = t; i < 4096; i += 512) { const int r=i>>6, cc=i&63; T2[r*PST+cc] = (r==cc?13.0f:0.0f) - T3[r*PST+cc]; }
      __syncthreads();
      mm_nn8(Vb, T2, T3, t);  __syncthreads();
      for (int i = t; i < 4096; i += 512) { const int r=i>>6, cc=i&63; Vb[r*PST+cc] = 0.25f*T3[r*PST+cc]; }
      __syncthreads();
    }
    for (int i = t; i < 4096; i += 512) a2inv[(long)bh*4096 + i] = Vb[(i>>6)*PST + (i&63)];
    return;
  }
  // ---- attn3v partials: 8 blocks per (b,h), 512 tokens each ----
  float* Zlp = (float*)smem;               // [4][64][64]
  float* Slp = (float*)(smem + 65536);     // [4][64]
  char*  Plb = smem + 66560;               // [4][64][80B]
  const int abid = blockIdx.x - 64;
  const int bh = abid >> 3, qt = abid & 7;
  if (t < 256) {
    const int w = t >> 6, lane = t & 63;
    const int c = lane & 15, g = lane >> 4;
    s16x8 aq[4][2];
    const u16* qlp = qlb + (long)bh*4096;
    #pragma unroll
    for (int mi = 0; mi < 4; ++mi)
      #pragma unroll
      for (int ks = 0; ks < 2; ++ks)
        aq[mi][ks] = ld8(qlp + (mi*16 + c)*64 + ks*32 + g*8);

    f32x4 zacc[4][4] = {};
    float sl[4][4] = {};
    const u16* kp = kk + (long)bh*NTOK*DH;
    const u16* vp = vt + (long)bh*DH*NTOK;
    char* pbase = Plb + w*5120;
    const int tok00 = qt*512 + w*128;

    for (int it = 0; it < 4; ++it) {
      const int t0 = tok00 + it*32;
      f32x4 sacc[4][2] = {};
      s16x8 kb[2][2];
      #pragma unroll
      for (int cg = 0; cg < 2; ++cg)
        #pragma unroll
        for (int ks = 0; ks < 2; ++ks)
          kb[cg][ks] = ld8(kp + (long)(t0 + cg*16 + c)*64 + ks*32 + g*8);
      #pragma unroll
      for (int cg = 0; cg < 2; ++cg)
        #pragma unroll
        for (int ks = 0; ks < 2; ++ks)
          #pragma unroll
          for (int mi = 0; mi < 4; ++mi)
            sacc[mi][cg] = __builtin_amdgcn_mfma_f32_16x16x32_bf16(aq[mi][ks], kb[cg][ks], sacc[mi][cg], 0, 0, 0);
      #pragma unroll
      for (int mi = 0; mi < 4; ++mi)
        #pragma unroll
        for (int r = 0; r < 4; ++r) {
          const int row = mi*16 + g*4 + r;
          const float p0 = __expf(sacc[mi][0][r]);
          const float p1 = __expf(sacc[mi][1][r]);
          sl[mi][r] += p0 + p1;
          char* base = pbase + row*80;
          *(u16*)(base + c*2)      = f2b(p0);
          *(u16*)(base + 32 + c*2) = f2b(p1);
        }
      s16x8 pa[4];
      #pragma unroll
      for (int mi = 0; mi < 4; ++mi) pa[mi] = *(const s16x8*)(pbase + (mi*16 + c)*80 + g*16);
      #pragma unroll
      for (int ni = 0; ni < 4; ++ni) {
        const s16x8 vb = ld8(vp + (long)(ni*16 + c)*NTOK + t0 + g*8);
        #pragma unroll
        for (int mi = 0; mi < 4; ++mi)
          zacc[mi][ni] = __builtin_amdgcn_mfma_f32_16x16x32_bf16(pa[mi], vb, zacc[mi][ni], 0, 0, 0);
      }
    }
    #pragma unroll
    for (int mi = 0; mi < 4; ++mi)
      #pragma unroll
      for (int r = 0; r < 4; ++r) {
        float s = sl[mi][r];
        s += __shfl_xor(s, 1); s += __shfl_xor(s, 2); s += __shfl_xor(s, 4); s += __shfl_xor(s, 8);
        sl[mi][r] = s;
      }
    #pragma unroll
    for (int mi = 0; mi < 4; ++mi)
      #pragma unroll
      for (int ni = 0; ni < 4; ++ni)
        #pragma unroll
        for (int r = 0; r < 4; ++r)
          Zlp[w*4096 + (mi*16 + g*4 + r)*64 + ni*16 + c] = zacc[mi][ni][r];
    if (c == 0)
      #pragma unroll
      for (int mi = 0; mi < 4; ++mi)
        #pragma unroll
        for (int r = 0; r < 4; ++r)
          Slp[w*64 + mi*16 + g*4 + r] = sl[mi][r];
  }
  __syncthreads();
  float* zpp = zp + (long)abid*4096;
  for (int i = t; i < 4096; i += 512)
    zpp[i] = Zlp[i] + Zlp[4096 + i] + Zlp[8192 + i] + Zlp[12288 + i];
  if (t < 64) sp[(long)abid*64 + t] = Slp[t] + Slp[64 + t] + Slp[128 + t] + Slp[192 + t];
}

// ---------------- fused: z-reduce + W2^T = (attn2inv @ z)^T  (bf16 [dh][lm], 1024 thr) ----------------
__global__ __launch_bounds__(1024) void k_w2(const float* __restrict__ a2inv,
                                             const float* __restrict__ zp, const float* __restrict__ sp,
                                             u16* __restrict__ w2t) {
  __shared__ __align__(16) float Ai[64*PST];
  __shared__ __align__(16) float Zi[64*PST];
  __shared__ __align__(16) float Ci[64*PST];
  __shared__ float Ss[64];
  const int bh = blockIdx.x, t = threadIdx.x;
  if (t < 64) {
    float ss = 0.f;
    #pragma unroll
    for (int qt = 0; qt < 8; ++qt) ss += sp[(long)(bh*8 + qt)*64 + t];
    Ss[t] = 1.0f / ss;
  }
  for (int i = t; i < 4096; i += 1024)
    Ai[(i>>6)*PST + (i&63)] = a2inv[(long)bh*4096 + i];
  __syncthreads();
  for (int i = t; i < 4096; i += 1024) {
    float zs = 0.f;
    #pragma unroll
    for (int qt = 0; qt < 8; ++qt) zs += zp[((long)(bh*8 + qt))*4096 + i];
    Zi[(i>>6)*PST + (i&63)] = zs * Ss[i>>6];
  }
  __syncthreads();
  mm_nn4(Ai, Zi, Ci, t);
  __syncthreads();
  for (int i = t; i < 4096; i += 1024) { const int r = i>>6, cc = i&63; w2t[(long)bh*4096 + cc*64 + r] = f2b(Ci[r*PST + cc]); }
}

// ---------------- out_h = softmax(q @ k_l^T) @ W2, fused, writes attnout bf16 ----------------
#define P1ST 144
__global__ __launch_bounds__(256) void k_attn1(const u16* __restrict__ q, const u16* __restrict__ klb,
                                               const u16* __restrict__ w2t, u16* __restrict__ ao) {
  __shared__ __align__(16) u16 Pl[4][64][72];
  const int bx = blockIdx.x, bh = bx >> 4, tt = bx & 15;
  const int b = bh >> 4, h = bh & 15;
  const int t = threadIdx.x, w = t >> 6, lane = t & 63;
  const int c = lane & 15, g = lane >> 4;
  const int tok0 = tt*256 + w*64;
  const u16* qp  = q + ((long)bh*NTOK + tok0)*DH;
  const u16* klp = klb + (long)bh*4096;
  const u16* wp  = w2t + (long)bh*4096;
  char* pbase = (char*)&Pl[w][0][0];

  s16x8 aq[4][2], kb[4][2], wb[4][2];
  #pragma unroll
  for (int i = 0; i < 4; ++i)
    #pragma unroll
    for (int ks = 0; ks < 2; ++ks) {
      aq[i][ks] = ld8(qp + (long)(i*16 + c)*DH + ks*32 + g*8);
      kb[i][ks] = ld8(klp + (i*16 + c)*64 + ks*32 + g*8);
      wb[i][ks] = ld8(wp  + (i*16 + c)*64 + ks*32 + g*8);
    }
  f32x4 sacc[4][4] = {};
  #pragma unroll
  for (int ks = 0; ks < 2; ++ks)
    #pragma unroll
    for (int mi = 0; mi < 4; ++mi)
      #pragma unroll
      for (int ni = 0; ni < 4; ++ni)
        sacc[mi][ni] = __builtin_amdgcn_mfma_f32_16x16x32_bf16(aq[mi][ks], kb[ni][ks], sacc[mi][ni], 0, 0, 0);

  float rs[4][4];
  #pragma unroll
  for (int mi = 0; mi < 4; ++mi)
    #pragma unroll
    for (int r = 0; r < 4; ++r) {
      const int row = mi*16 + g*4 + r;
      char* base = pbase + row*P1ST;
      float ssum = 0.f;
      #pragma unroll
      for (int ni = 0; ni < 4; ++ni) {
        const float p = __expf(sacc[mi][ni][r]);
        ssum += p;
        *(u16*)(base + (ni*16 + c)*2) = f2b(p);
      }
      ssum += __shfl_xor(ssum, 1); ssum += __shfl_xor(ssum, 2);
      ssum += __shfl_xor(ssum, 4); ssum += __shfl_xor(ssum, 8);
      rs[mi][r] = ssum;
    }
  __builtin_amdgcn_s_barrier();
  s16x8 pa[4][2];
  #pragma unroll
  for (int mi = 0; mi < 4; ++mi)
    #pragma unroll
    for (int ks = 0; ks < 2; ++ks)
      pa[mi][ks] = *(const s16x8*)(pbase + (mi*16 + c)*P1ST + ks*64 + g*16);
  f32x4 oacc[4][4] = {};
  #pragma unroll
  for (int ks = 0; ks < 2; ++ks)
    #pragma unroll
    for (int mi = 0; mi < 4; ++mi)
      #pragma unroll
      for (int ni = 0; ni < 4; ++ni)
        oacc[mi][ni] = __builtin_amdgcn_mfma_f32_16x16x32_bf16(pa[mi][ks], wb[ni][ks], oacc[mi][ni], 0, 0, 0);

  u16* op = ao + (long)b*NTOK*DM + (long)h*64;
  #pragma unroll
  for (int mi = 0; mi < 4; ++mi)
    #pragma unroll
    for (int r = 0; r < 4; ++r) {
      const int tok = tok0 + mi*16 + g*4 + r;
      const float inv = 1.0f / rs[mi][r];
      #pragma unroll
      for (int ni = 0; ni < 4; ++ni)
        op[(long)tok*DM + ni*16 + c] = f2b(oacc[mi][ni][r] * inv);
    }
}

extern "C" void kernel_launch(void* const* d_in, const int* in_sizes, int n_in,
                              void* d_out, int out_size, void* d_ws, size_t ws_size,
                              hipStream_t stream) {
  const float* hs   = (const float*)d_in[0];
  const float* Wqkv = (const float*)d_in[1];
  const float* bqkv = (const float*)d_in[2];
  const float* Wout = (const float*)d_in[3];
  const float* bout = (const float*)d_in[4];
  float* out = (float*)d_out;
  char* w = (char*)d_ws;

  u16*  Xb    = (u16*)(w);                 // 32MB; dead after gemm0
  float* zp   = (float*)(w);               // aliases Xb (written by k_pa after gemm0), 8MB
  float* sp   = (float*)(w + 8388608L);
  u16*  WqkvT = (u16*)(w + 33554432L);
  u16*  WoutT = (u16*)(w + 39845888L);
  u16*  q     = (u16*)(w + 41943040L);
  float* psum = (float*)(w + 41943040L);   // aliases q: consumed by k_lreduce BEFORE gemm0 writes q
  u16*  k     = (u16*)(w + 75497472L);
  float* Xl   = (float*)(w + 109051904L);
  u16*  vt    = (u16*)(w + 142606336L);    // written directly by gemm0's V epilogue
  float* qlf  = (float*)(w + 176160768L);
  float* klf  = (float*)(w + 177209344L);
  u16*  qlb   = (u16*)(w + 178257920L);
  u16*  klb   = (u16*)(w + 178782208L);
  float* a2i  = (float*)(w + 179306496L);
  u16*  w2t   = (u16*)(w + 181403648L);
  u16*  ao    = (u16*)(w + 181927936L);

  k_pre<<<2048, 256, 0, stream>>>(hs, Xb, Xl, Wqkv, WqkvT, Wout, WoutT);
  k_lproj2<<<dim3(8,8,8), 256, 0, stream>>>(Xl, Wqkv, psum);
  k_lreduce<<<2048, 256, 0, stream>>>(psum, bqkv, qlf, klf, qlb, klb);
  k_gemm256<0><<<dim3(64,12), 512, 0, stream>>>(Xb, WqkvT, bqkv, 3072, nullptr, q, k, vt);
  k_pa<<<576, 512, 0, stream>>>(qlf, klf, a2i, qlb, k, vt, zp, sp);
  k_w2<<<64, 1024, 0, stream>>>(a2i, zp, sp, w2t);
  k_attn1<<<1024, 256, 0, stream>>>(q, klb, w2t, ao);
  k_gemm256<1><<<dim3(64,4), 512, 0, stream>>>(ao, WoutT, bout, 1024, out, nullptr, nullptr, nullptr);
}

// Round 12
// 324.894 us; speedup vs baseline: 5.9947x; 1.0300x over previous
//
#include <hip/hip_runtime.h>
#include <cstdint>

typedef unsigned short u16;
typedef __attribute__((ext_vector_type(8))) short s16x8;
typedef __attribute__((ext_vector_type(4))) float f32x4;

#define NTOK 4096
#define DH   64
#define DM   1024
#define NH   16

static __device__ __forceinline__ float b2f(u16 u){ return __uint_as_float(((unsigned)u)<<16); }
static __device__ __forceinline__ u16 f2b(float f){
  unsigned u = __float_as_uint(f);
  return (u16)((u + 0x7FFFu + ((u>>16)&1u)) >> 16);   // RNE
}

static __device__ __forceinline__ void gload_lds16(const void* g, void* l) {
  __builtin_amdgcn_global_load_lds(
      (const __attribute__((address_space(1))) unsigned*)(uintptr_t)g,
      (__attribute__((address_space(3))) unsigned*)(uintptr_t)l, 16, 0, 0);
}

static __device__ __forceinline__ s16x8 ld8(const u16* p){ return *(const s16x8*)(const void*)p; }

// ---------------- merged pre-pass: cvt_xl (1024 blks) | cvt_t Wqkv (768) | cvt_t Wout (256) ----------------
__global__ __launch_bounds__(256) void k_pre(const float* __restrict__ hs, u16* __restrict__ Xb,
                                             float* __restrict__ Xl,
                                             const float* __restrict__ Wqkv, u16* __restrict__ WqkvT,
                                             const float* __restrict__ Wout, u16* __restrict__ WoutT) {
  __shared__ float tile[64][65];
  const int bid = blockIdx.x, t = threadIdx.x;
  if (bid < 1024) {
    const int grp = bid >> 2;
    const int d = (bid & 3)*256 + t;
    const float* p = hs + (long)grp*64*DM + d;
    u16* xo = Xb + (long)grp*64*DM + d;
    float s = 0.f;
    #pragma unroll 8
    for (int i = 0; i < 64; ++i) {
      const float v = p[(long)i*DM];
      s += v;
      xo[(long)i*DM] = f2b(v);
    }
    Xl[(long)grp*DM + d] = s * (1.0f/64.0f);
    return;
  }
  const float* in; u16* out; int R, C, tc, tr;
  if (bid < 1792) { const int x = bid - 1024; in = Wqkv; out = WqkvT; R = 1024; C = 3072; tc = x % 48; tr = x / 48; }
  else            { const int x = bid - 1792; in = Wout; out = WoutT; R = 1024; C = 1024; tc = x & 15;  tr = x >> 4; }
  const int cx = t & 63, ry = t >> 6;
  #pragma unroll
  for (int p = 0; p < 16; ++p) {
    const int row = p*4 + ry;
    tile[row][cx] = in[(long)(tr*64 + row)*C + tc*64 + cx];
  }
  __syncthreads();
  #pragma unroll
  for (int p = 0; p < 16; ++p) {
    const int orow = p*4 + ry;
    out[(long)(tc*64 + orow)*R + tr*64 + cx] = f2b(tile[cx][orow]);
  }
}

// ---------------- fp32 projection, K-split: psum[z][row][col] partials ----------------
__global__ __launch_bounds__(256) void k_lproj2(const float* __restrict__ Xl, const float* __restrict__ Wqkv,
                                                float* __restrict__ psum) {
  __shared__ __align__(16) float Xs[32][68];
  const int t = threadIdx.x;
  const int wcol = blockIdx.x*256 + t;    // 0..2047
  const int r0 = blockIdx.y*32;
  const int kbase = blockIdx.z*128;
  float acc[32];
  #pragma unroll
  for (int r = 0; r < 32; ++r) acc[r] = 0.f;
  for (int k0 = kbase; k0 < kbase + 128; k0 += 64) {
    __syncthreads();
    for (int idx = t; idx < 2048; idx += 256)
      Xs[idx>>6][idx&63] = Xl[(long)(r0 + (idx>>6))*DM + k0 + (idx&63)];
    __syncthreads();
    for (int kk = 0; kk < 64; kk += 4) {
      f32x4 wv;
      #pragma unroll
      for (int j = 0; j < 4; ++j) wv[j] = Wqkv[(long)(k0+kk+j)*3072 + wcol];
      #pragma unroll
      for (int r = 0; r < 32; ++r) {
        const f32x4 xv = *(const f32x4*)&Xs[r][kk];
        acc[r] += xv[0]*wv[0] + xv[1]*wv[1] + xv[2]*wv[2] + xv[3]*wv[3];
      }
    }
  }
  float* po = psum + ((long)blockIdx.z*256 + r0)*2048 + wcol;
  #pragma unroll
  for (int r = 0; r < 32; ++r) po[(long)r*2048] = acc[r];
}

// ---------------- reduce K-slices + bias + scale -> qlf/klf/qlb/klb ----------------
__global__ __launch_bounds__(256) void k_lreduce(const float* __restrict__ psum, const float* __restrict__ bqkv,
                                                 float* __restrict__ qlf, float* __restrict__ klf,
                                                 u16* __restrict__ qlb, u16* __restrict__ klb) {
  const long idx = (long)blockIdx.x*256 + threadIdx.x;
  const int row = (int)(idx >> 11), col = (int)(idx & 2047);
  float s = 0.f;
  #pragma unroll
  for (int z = 0; z < 8; ++z) s += psum[((long)z*256 + row)*2048 + col];
  const int isq = (col < 1024) ? 1 : 0;
  float val = s + bqkv[col];
  if (isq) val *= 0.125f;
  const int b = row >> 6, lm = row & 63;
  const int c2 = col & 1023, h = c2 >> 6, dh = c2 & 63;
  const long o = (((long)b*NH + h)*64 + lm)*64 + dh;
  if (isq) { qlf[o] = val; qlb[o] = f2b(val); }
  else     { klf[o] = val; klb[o] = f2b(val); }
}

// ---------------- GEMM 256x256, BK=64, 8 waves, 2x64KB dbuf, 8-phase m201-style schedule ----------------
// r12: per iteration (64 K): 4 phases x {ds_read subtile; stage 1 half-tile (2 gloads);
//   barrier; lgkmcnt(0); setprio(1) 16 MFMA setprio(0); [vmcnt] barrier}.
// Stage order per iter: B-ht0, B-ht1, A-ht0, A-ht1 (for next dbuf). FIFO ledger:
//   vmcnt(2) before P0/P3 post-MFMA barriers retires exactly what the next phase reads;
//   never drained to 0 except the final iteration.
// LDS rows are 128B; chunk-XOR swizzle p=(ks*4+g)^(row&7) with pre-swizzled global source
//   (linear LDS dst as global_load_lds requires); quarter-wave banks 2-way = free.
template<int EPI>
__global__ __launch_bounds__(512, 2) void k_gemm256(
    const u16* __restrict__ A, const u16* __restrict__ Bt, const float* __restrict__ bias,
    int N, float* __restrict__ outF, u16* __restrict__ outQ, u16* __restrict__ outK, u16* __restrict__ outV)
{
  __shared__ __align__(16) u16 lds[2*32768];
  const int t = threadIdx.x;
  const int lane = t & 63;
  const int wid = t >> 6;
  const int c = lane & 15, g = lane >> 4;
  const int wm = wid >> 2, wn = wid & 3;
  const int fid = blockIdx.y*64 + blockIdx.x;
  const int nbx = ((fid & 7) << 3) | ((fid >> 3) & 7);
  const int nby = fid >> 6;
  const long arow0 = (long)nbx * 256;
  const long brow0 = (long)nby * 256;
  char* ldsb = (char*)lds;

  // staging: thread t -> rows (t>>3) and (t>>3)+64 of a 128-row half-tile, chunk gch (pre-swizzled)
  const int srow3 = t >> 3;                       // 0..63
  const int sch = ((t & 7) ^ (srow3 & 7)) * 8;    // element offset of 16B chunk
  const u16* sA = A  + (arow0 + srow3)*1024 + sch;
  const u16* sB = Bt + (brow0 + srow3)*1024 + sch;
  const int dbase = t*16;

#define STG(gp, R0, Toff, kbe, nb) { \
    char* d0 = ldsb + (nb)*65536 + (Toff) + (R0)*128 + dbase; \
    gload_lds16((gp) + (long)(R0)*1024 + (kbe), d0); \
    gload_lds16((gp) + (long)((R0)+64)*1024 + (kbe), d0 + 8192); }

  // read offsets: row part + swizzled chunk part (row&7 == c&7 for all frag rows)
  const int cp0 = ((g     ) ^ (c & 7)) * 16;      // ks=0
  const int cp1 = ((4 | g ) ^ (c & 7)) * 16;      // ks=1
  int rowA[4], rowB[4];
  #pragma unroll
  for (int mi = 0; mi < 4; ++mi) {
    rowA[mi] = (wm*64 + mi*16 + c)*128;
    rowB[mi] = 32768 + (wn*64 + mi*16 + c)*128;
  }

  f32x4 acc0[4][4] = {};
  f32x4 acc1[4][4] = {};

  // prologue: stage dbuf0 (B0,B1,A0,A1); retire B0,B1,A0 (keep A1 in flight)
  STG(sB, 0, 32768, 0, 0)
  STG(sB, 128, 32768, 0, 0)
  STG(sA, 0, 0, 0, 0)
  STG(sA, 128, 0, 0, 0)
  asm volatile("s_waitcnt vmcnt(2)" ::: "memory");
  __builtin_amdgcn_s_barrier();

  for (int it = 0; it < 16; ++it) {
    char* buf = ldsb + (it&1)*65536;
    const int nb = (it+1)&1;
    const int kb1 = (it+1)*64;
    const bool last = (it == 15);
    s16x8 fa[4], fb[4], ga[4];
    // ---- P0: acc0 x ks0 (A band0 + B), stage B-ht0' ----
    #pragma unroll
    for (int mi = 0; mi < 4; ++mi) fa[mi] = *(const s16x8*)(buf + rowA[mi] + cp0);
    #pragma unroll
    for (int ni = 0; ni < 4; ++ni) fb[ni] = *(const s16x8*)(buf + rowB[ni] + cp0);
    if (!last) STG(sB, 0, 32768, kb1, nb)
    __builtin_amdgcn_s_barrier();
    asm volatile("s_waitcnt lgkmcnt(0)" ::: "memory");
    __builtin_amdgcn_sched_barrier(0);
    __builtin_amdgcn_s_setprio(1);
    #pragma unroll
    for (int mi = 0; mi < 4; ++mi)
      #pragma unroll
      for (int ni = 0; ni < 4; ++ni)
        acc0[mi][ni] = __builtin_amdgcn_mfma_f32_16x16x32_bf16(fa[mi], fb[ni], acc0[mi][ni], 0, 0, 0);
    __builtin_amdgcn_s_setprio(0);
    if (last) { asm volatile("s_waitcnt vmcnt(0)" ::: "memory"); }
    else      { asm volatile("s_waitcnt vmcnt(2)" ::: "memory"); }
    __builtin_amdgcn_s_barrier();
    // ---- P1: acc1 x ks0 (A band1; B reused), stage B-ht1' ----
    #pragma unroll
    for (int mi = 0; mi < 4; ++mi) ga[mi] = *(const s16x8*)(buf + rowA[mi] + 16384 + cp0);
    if (!last) STG(sB, 128, 32768, kb1, nb)
    __builtin_amdgcn_s_barrier();
    asm volatile("s_waitcnt lgkmcnt(0)" ::: "memory");
    __builtin_amdgcn_sched_barrier(0);
    __builtin_amdgcn_s_setprio(1);
    #pragma unroll
    for (int mi = 0; mi < 4; ++mi)
      #pragma unroll
      for (int ni = 0; ni < 4; ++ni)
        acc1[mi][ni] = __builtin_amdgcn_mfma_f32_16x16x32_bf16(ga[mi], fb[ni], acc1[mi][ni], 0, 0, 0);
    __builtin_amdgcn_s_setprio(0);
    __builtin_amdgcn_s_barrier();
    // ---- P2: acc0 x ks1, stage A-ht0' ----
    #pragma unroll
    for (int mi = 0; mi < 4; ++mi) fa[mi] = *(const s16x8*)(buf + rowA[mi] + cp1);
    #pragma unroll
    for (int ni = 0; ni < 4; ++ni) fb[ni] = *(const s16x8*)(buf + rowB[ni] + cp1);
    if (!last) STG(sA, 0, 0, kb1, nb)
    __builtin_amdgcn_s_barrier();
    asm volatile("s_waitcnt lgkmcnt(0)" ::: "memory");
    __builtin_amdgcn_sched_barrier(0);
    __builtin_amdgcn_s_setprio(1);
    #pragma unroll
    for (int mi = 0; mi < 4; ++mi)
      #pragma unroll
      for (int ni = 0; ni < 4; ++ni)
        acc0[mi][ni] = __builtin_amdgcn_mfma_f32_16x16x32_bf16(fa[mi], fb[ni], acc0[mi][ni], 0, 0, 0);
    __builtin_amdgcn_s_setprio(0);
    __builtin_amdgcn_s_barrier();
    // ---- P3: acc1 x ks1, stage A-ht1' ----
    #pragma unroll
    for (int mi = 0; mi < 4; ++mi) ga[mi] = *(const s16x8*)(buf + rowA[mi] + 16384 + cp1);
    if (!last) STG(sA, 128, 0, kb1, nb)
    __builtin_amdgcn_s_barrier();
    asm volatile("s_waitcnt lgkmcnt(0)" ::: "memory");
    __builtin_amdgcn_sched_barrier(0);
    __builtin_amdgcn_s_setprio(1);
    #pragma unroll
    for (int mi = 0; mi < 4; ++mi)
      #pragma unroll
      for (int ni = 0; ni < 4; ++ni)
        acc1[mi][ni] = __builtin_amdgcn_mfma_f32_16x16x32_bf16(ga[mi], fb[ni], acc1[mi][ni], 0, 0, 0);
    __builtin_amdgcn_s_setprio(0);
    if (!last) { asm volatile("s_waitcnt vmcnt(2)" ::: "memory"); }
    __builtin_amdgcn_s_barrier();
  }
#undef STG

  if (EPI == 0) {
    const int tensor = (int)(brow0 >> 10);
    if (tensor == 2) {
      // V: write transposed vt[bh][dh][tok] via per-wave LDS transpose (dbuf LDS dead)
      __syncthreads();
      u16* wlds = lds + wid*4224;                       // 64*66 u16 per wave
      const int hbase = (int)((brow0 + wn*64) & 1023);
      const int head = hbase >> 6;
      #pragma unroll
      for (int ph = 0; ph < 2; ++ph) {
        const long grow0 = arow0 + ph*128 + wm*64;
        const int b = (int)(grow0 >> 12), tok0r = (int)(grow0 & 4095);
        #pragma unroll
        for (int mi = 0; mi < 4; ++mi)
          #pragma unroll
          for (int ni = 0; ni < 4; ++ni) {
            const float bv = bias[brow0 + wn*64 + ni*16 + c];
            const f32x4 a = ph ? acc1[mi][ni] : acc0[mi][ni];
            #pragma unroll
            for (int r = 0; r < 4; ++r)
              wlds[(mi*16 + g*4 + r)*66 + ni*16 + c] = f2b(a[r] + bv);
          }
        asm volatile("s_waitcnt lgkmcnt(0)" ::: "memory");
        u16* vbase = outV + (((long)b*NH + head)*DH)*NTOK + tok0r;
        #pragma unroll
        for (int j = 0; j < 8; ++j) {
          const int d = j*8 + (lane >> 3);
          const int tk = (lane & 7)*8;
          s16x8 vv;
          #pragma unroll
          for (int s2 = 0; s2 < 8; ++s2) vv[s2] = (short)wlds[(tk + s2)*66 + d];
          *(s16x8*)(vbase + (long)d*NTOK + tk) = vv;
        }
        asm volatile("s_waitcnt lgkmcnt(0)" ::: "memory");
      }
    } else {
      u16* dst = (tensor == 0) ? outQ : outK;
      const float mul = (tensor == 0) ? 0.125f : 1.0f;
      #pragma unroll
      for (int ph = 0; ph < 2; ++ph)
        #pragma unroll
        for (int mi = 0; mi < 4; ++mi) {
          const int rowb = ph*128 + wm*64 + mi*16 + g*4;
          #pragma unroll
          for (int ni = 0; ni < 4; ++ni) {
            const long gcol = brow0 + wn*64 + ni*16 + c;
            const int c2 = (int)(gcol & 1023);
            const int head = c2 >> 6, dh = c2 & 63;
            const float bv = bias[gcol];
            const f32x4 a = ph ? acc1[mi][ni] : acc0[mi][ni];
            #pragma unroll
            for (int r = 0; r < 4; ++r) {
              const long grow = arow0 + rowb + r;
              const int b = (int)(grow >> 12), tok = (int)(grow & 4095);
              dst[(((long)b*NH + head)*NTOK + tok)*DH + dh] = f2b((a[r] + bv)*mul);
            }
          }
        }
    }
  } else {
    #pragma unroll
    for (int ph = 0; ph < 2; ++ph)
      #pragma unroll
      for (int mi = 0; mi < 4; ++mi) {
        const int rowb = ph*128 + wm*64 + mi*16 + g*4;
        #pragma unroll
        for (int ni = 0; ni < 4; ++ni) {
          const long gcol = brow0 + wn*64 + ni*16 + c;
          const float bv = bias[gcol];
          const f32x4 a = ph ? acc1[mi][ni] : acc0[mi][ni];
          #pragma unroll
          for (int r = 0; r < 4; ++r) {
            const long grow = arow0 + rowb + r;
            outF[grow*N + gcol] = a[r] + bv;
          }
        }
      }
  }
}

// ---------------- fp32 LDS 64x64 matmul helpers ----------------
#define PST 68
static __device__ __forceinline__ void mm_nn8(const float* A, const float* B, float* C, int t) {
  const int lane = t & 63, j0 = (t >> 6) << 3;
  float acc[8];
  #pragma unroll
  for (int j = 0; j < 8; ++j) acc[j] = 0.f;
  for (int k = 0; k < 64; k += 4) {
    const f32x4 a4 = *(const f32x4*)&A[lane*PST + k];
    #pragma unroll
    for (int dk = 0; dk < 4; ++dk) {
      const float a = a4[dk];
      const float* br = &B[(k + dk)*PST + j0];
      const f32x4 b0 = *(const f32x4*)(br);
      const f32x4 b1 = *(const f32x4*)(br + 4);
      #pragma unroll
      for (int qq = 0; qq < 4; ++qq) { acc[qq] += a*b0[qq]; acc[4+qq] += a*b1[qq]; }
    }
  }
  #pragma unroll
  for (int j = 0; j < 8; ++j) C[lane*PST + j0 + j] = acc[j];
}
static __device__ __forceinline__ void mm_nt8(const float* A, const float* B, float* C, int t) {
  const int lane = t & 63, j0 = (t >> 6) << 3;
  float acc[8];
  #pragma unroll
  for (int j = 0; j < 8; ++j) acc[j] = 0.f;
  for (int k = 0; k < 64; k += 4) {
    const f32x4 a4 = *(const f32x4*)&A[lane*PST + k];
    #pragma unroll
    for (int jj = 0; jj < 8; ++jj) {
      const f32x4 b4 = *(const f32x4*)&B[(j0 + jj)*PST + k];
      acc[jj] += a4[0]*b4[0] + a4[1]*b4[1] + a4[2]*b4[2] + a4[3]*b4[3];
    }
  }
  #pragma unroll
  for (int j = 0; j < 8; ++j) C[lane*PST + j0 + j] = acc[j];
}
static __device__ __forceinline__ void mm_nn4(const float* A, const float* B, float* C, int t) {
  const int lane = t & 63, j0 = (t >> 6) << 2;
  float acc[4] = {0.f, 0.f, 0.f, 0.f};
  for (int k = 0; k < 64; k += 4) {
    const f32x4 a4 = *(const f32x4*)&A[lane*PST + k];
    #pragma unroll
    for (int dk = 0; dk < 4; ++dk) {
      const f32x4 b0 = *(const f32x4*)&B[(k + dk)*PST + j0];
      #pragma unroll
      for (int q = 0; q < 4; ++q) acc[q] += a4[dk]*b0[q];
    }
  }
  #pragma unroll
  for (int j = 0; j < 4; ++j) C[lane*PST + j0 + j] = acc[j];
}

// ---------------- merged: pinv (blocks 0..63) | attn3v partials (blocks 64..575) ----------------
__global__ __launch_bounds__(512) void k_pa(const float* __restrict__ qlf, const float* __restrict__ klf,
                                            float* __restrict__ a2inv,
                                            const u16* __restrict__ qlb, const u16* __restrict__ kk,
                                            const u16* __restrict__ vt,
                                            float* __restrict__ zp, float* __restrict__ sp) {
  __shared__ __align__(16) char smem[87040];
  const int t = threadIdx.x;
  if (blockIdx.x < 64) {
    float* Xb = (float*)smem;
    float* Vb = Xb + 64*PST;
    float* T1 = Vb + 64*PST;
    float* T2 = T1 + 64*PST;
    float* T3 = T2 + 64*PST;
    const int bh = blockIdx.x;
    const float* ql = qlf + (long)bh*4096;
    const float* kl = klf + (long)bh*4096;
    for (int i = t; i < 4096; i += 512) { T1[(i>>6)*PST + (i&63)] = ql[i]; T2[(i>>6)*PST + (i&63)] = kl[i]; }
    __syncthreads();
    mm_nt8(T1, T2, Xb, t);
    __syncthreads();
    if (t < 64) {
      float mx = -1e30f;
      for (int j = 0; j < 64; ++j) mx = fmaxf(mx, Xb[t*PST + j]);
      float s = 0.f;
      for (int j = 0; j < 64; ++j) { const float e = expf(Xb[t*PST + j] - mx); Xb[t*PST + j] = e; s += e; }
      const float inv = 1.0f/s;
      for (int j = 0; j < 64; ++j) Xb[t*PST + j] *= inv;
    }
    __syncthreads();
    for (int i = t; i < 4096; i += 512) { const int r = i>>6, cc = i&63; Vb[r*PST+cc] = Xb[r*PST+cc]; }
    __syncthreads();
    for (int it = 0; it < 6; ++it) {
      mm_nn8(Xb, Vb, T1, t);  __syncthreads();
      for (int i = t; i < 4096; i += 512) { const int r=i>>6, cc=i&63; T2[r*PST+cc] = (r==cc?7.0f:0.0f) - T1[r*PST+cc]; }
      __syncthreads();
      mm_nn8(T1, T2, T3, t);  __syncthreads();
      for (int i = t; i < 4096; i += 512) { const int r=i>>6, cc=i&63; T2[r*PST+cc] = (r==cc?15.0f:0.0f) - T3[r*PST+cc]; }
      __syncthreads();
      mm_nn8(T1, T2, T3, t);  __syncthreads();
      for (int i = t; i < 4096; i += 512) { const int r=i>>6, cc=i&63; T2[r*PST+cc] = (r==cc?13.0f:0.0f) - T3[r*PST+cc]; }
      __syncthreads();
      mm_nn8(Vb, T2, T3, t);  __syncthreads();
      for (int i = t; i < 4096; i += 512) { const int r=i>>6, cc=i&63; Vb[r*PST+cc] = 0.25f*T3[r*PST+cc]; }
      __syncthreads();
    }
    for (int i = t; i < 4096; i += 512) a2inv[(long)bh*4096 + i] = Vb[(i>>6)*PST + (i&63)];
    return;
  }
  float* Zlp = (float*)smem;               // [4][64][64]
  float* Slp = (float*)(smem + 65536);     // [4][64]
  char*  Plb = smem + 66560;               // [4][64][80B]
  const int abid = blockIdx.x - 64;
  const int bh = abid >> 3, qt = abid & 7;
  if (t < 256) {
    const int w = t >> 6, lane = t & 63;
    const int c = lane & 15, g = lane >> 4;
    s16x8 aq[4][2];
    const u16* qlp = qlb + (long)bh*4096;
    #pragma unroll
    for (int mi = 0; mi < 4; ++mi)
      #pragma unroll
      for (int ks = 0; ks < 2; ++ks)
        aq[mi][ks] = ld8(qlp + (mi*16 + c)*64 + ks*32 + g*8);

    f32x4 zacc[4][4] = {};
    float sl[4][4] = {};
    const u16* kp = kk + (long)bh*NTOK*DH;
    const u16* vp = vt + (long)bh*DH*NTOK;
    char* pbase = Plb + w*5120;
    const int tok00 = qt*512 + w*128;

    for (int it = 0; it < 4; ++it) {
      const int t0 = tok00 + it*32;
      f32x4 sacc[4][2] = {};
      s16x8 kb[2][2];
      #pragma unroll
      for (int cg = 0; cg < 2; ++cg)
        #pragma unroll
        for (int ks = 0; ks < 2; ++ks)
          kb[cg][ks] = ld8(kp + (long)(t0 + cg*16 + c)*64 + ks*32 + g*8);
      #pragma unroll
      for (int cg = 0; cg < 2; ++cg)
        #pragma unroll
        for (int ks = 0; ks < 2; ++ks)
          #pragma unroll
          for (int mi = 0; mi < 4; ++mi)
            sacc[mi][cg] = __builtin_amdgcn_mfma_f32_16x16x32_bf16(aq[mi][ks], kb[cg][ks], sacc[mi][cg], 0, 0, 0);
      #pragma unroll
      for (int mi = 0; mi < 4; ++mi)
        #pragma unroll
        for (int r = 0; r < 4; ++r) {
          const int row = mi*16 + g*4 + r;
          const float p0 = __expf(sacc[mi][0][r]);
          const float p1 = __expf(sacc[mi][1][r]);
          sl[mi][r] += p0 + p1;
          char* base = pbase + row*80;
          *(u16*)(base + c*2)      = f2b(p0);
          *(u16*)(base + 32 + c*2) = f2b(p1);
        }
      s16x8 pa[4];
      #pragma unroll
      for (int mi = 0; mi < 4; ++mi) pa[mi] = *(const s16x8*)(pbase + (mi*16 + c)*80 + g*16);
      #pragma unroll
      for (int ni = 0; ni < 4; ++ni) {
        const s16x8 vb = ld8(vp + (long)(ni*16 + c)*NTOK + t0 + g*8);
        #pragma unroll
        for (int mi = 0; mi < 4; ++mi)
          zacc[mi][ni] = __builtin_amdgcn_mfma_f32_16x16x32_bf16(pa[mi], vb, zacc[mi][ni], 0, 0, 0);
      }
    }
    #pragma unroll
    for (int mi = 0; mi < 4; ++mi)
      #pragma unroll
      for (int r = 0; r < 4; ++r) {
        float s = sl[mi][r];
        s += __shfl_xor(s, 1); s += __shfl_xor(s, 2); s += __shfl_xor(s, 4); s += __shfl_xor(s, 8);
        sl[mi][r] = s;
      }
    #pragma unroll
    for (int mi = 0; mi < 4; ++mi)
      #pragma unroll
      for (int ni = 0; ni < 4; ++ni)
        #pragma unroll
        for (int r = 0; r < 4; ++r)
          Zlp[w*4096 + (mi*16 + g*4 + r)*64 + ni*16 + c] = zacc[mi][ni][r];
    if (c == 0)
      #pragma unroll
      for (int mi = 0; mi < 4; ++mi)
        #pragma unroll
        for (int r = 0; r < 4; ++r)
          Slp[w*64 + mi*16 + g*4 + r] = sl[mi][r];
  }
  __syncthreads();
  float* zpp = zp + (long)abid*4096;
  for (int i = t; i < 4096; i += 512)
    zpp[i] = Zlp[i] + Zlp[4096 + i] + Zlp[8192 + i] + Zlp[12288 + i];
  if (t < 64) sp[(long)abid*64 + t] = Slp[t] + Slp[64 + t] + Slp[128 + t] + Slp[192 + t];
}

// ---------------- fused: z-reduce + W2^T = (attn2inv @ z)^T  (bf16 [dh][lm], 1024 thr) ----------------
__global__ __launch_bounds__(1024) void k_w2(const float* __restrict__ a2inv,
                                             const float* __restrict__ zp, const float* __restrict__ sp,
                                             u16* __restrict__ w2t) {
  __shared__ __align__(16) float Ai[64*PST];
  __shared__ __align__(16) float Zi[64*PST];
  __shared__ __align__(16) float Ci[64*PST];
  __shared__ float Ss[64];
  const int bh = blockIdx.x, t = threadIdx.x;
  if (t < 64) {
    float ss = 0.f;
    #pragma unroll
    for (int qt = 0; qt < 8; ++qt) ss += sp[(long)(bh*8 + qt)*64 + t];
    Ss[t] = 1.0f / ss;
  }
  for (int i = t; i < 4096; i += 1024)
    Ai[(i>>6)*PST + (i&63)] = a2inv[(long)bh*4096 + i];
  __syncthreads();
  for (int i = t; i < 4096; i += 1024) {
    float zs = 0.f;
    #pragma unroll
    for (int qt = 0; qt < 8; ++qt) zs += zp[((long)(bh*8 + qt))*4096 + i];
    Zi[(i>>6)*PST + (i&63)] = zs * Ss[i>>6];
  }
  __syncthreads();
  mm_nn4(Ai, Zi, Ci, t);
  __syncthreads();
  for (int i = t; i < 4096; i += 1024) { const int r = i>>6, cc = i&63; w2t[(long)bh*4096 + cc*64 + r] = f2b(Ci[r*PST + cc]); }
}

// ---------------- out_h = softmax(q @ k_l^T) @ W2, fused, writes attnout bf16 ----------------
#define P1ST 144
__global__ __launch_bounds__(256) void k_attn1(const u16* __restrict__ q, const u16* __restrict__ klb,
                                               const u16* __restrict__ w2t, u16* __restrict__ ao) {
  __shared__ __align__(16) u16 Pl[4][64][72];
  const int bx = blockIdx.x, bh = bx >> 4, tt = bx & 15;
  const int b = bh >> 4, h = bh & 15;
  const int t = threadIdx.x, w = t >> 6, lane = t & 63;
  const int c = lane & 15, g = lane >> 4;
  const int tok0 = tt*256 + w*64;
  const u16* qp  = q + ((long)bh*NTOK + tok0)*DH;
  const u16* klp = klb + (long)bh*4096;
  const u16* wp  = w2t + (long)bh*4096;
  char* pbase = (char*)&Pl[w][0][0];

  s16x8 aq[4][2], kb[4][2], wb[4][2];
  #pragma unroll
  for (int i = 0; i < 4; ++i)
    #pragma unroll
    for (int ks = 0; ks < 2; ++ks) {
      aq[i][ks] = ld8(qp + (long)(i*16 + c)*DH + ks*32 + g*8);
      kb[i][ks] = ld8(klp + (i*16 + c)*64 + ks*32 + g*8);
      wb[i][ks] = ld8(wp  + (i*16 + c)*64 + ks*32 + g*8);
    }
  f32x4 sacc[4][4] = {};
  #pragma unroll
  for (int ks = 0; ks < 2; ++ks)
    #pragma unroll
    for (int mi = 0; mi < 4; ++mi)
      #pragma unroll
      for (int ni = 0; ni < 4; ++ni)
        sacc[mi][ni] = __builtin_amdgcn_mfma_f32_16x16x32_bf16(aq[mi][ks], kb[ni][ks], sacc[mi][ni], 0, 0, 0);

  float rs[4][4];
  #pragma unroll
  for (int mi = 0; mi < 4; ++mi)
    #pragma unroll
    for (int r = 0; r < 4; ++r) {
      const int row = mi*16 + g*4 + r;
      char* base = pbase + row*P1ST;
      float ssum = 0.f;
      #pragma unroll
      for (int ni = 0; ni < 4; ++ni) {
        const float p = __expf(sacc[mi][ni][r]);
        ssum += p;
        *(u16*)(base + (ni*16 + c)*2) = f2b(p);
      }
      ssum += __shfl_xor(ssum, 1); ssum += __shfl_xor(ssum, 2);
      ssum += __shfl_xor(ssum, 4); ssum += __shfl_xor(ssum, 8);
      rs[mi][r] = ssum;
    }
  __builtin_amdgcn_s_barrier();
  s16x8 pa[4][2];
  #pragma unroll
  for (int mi = 0; mi < 4; ++mi)
    #pragma unroll
    for (int ks = 0; ks < 2; ++ks)
      pa[mi][ks] = *(const s16x8*)(pbase + (mi*16 + c)*P1ST + ks*64 + g*16);
  f32x4 oacc[4][4] = {};
  #pragma unroll
  for (int ks = 0; ks < 2; ++ks)
    #pragma unroll
    for (int mi = 0; mi < 4; ++mi)
      #pragma unroll
      for (int ni = 0; ni < 4; ++ni)
        oacc[mi][ni] = __builtin_amdgcn_mfma_f32_16x16x32_bf16(pa[mi][ks], wb[ni][ks], oacc[mi][ni], 0, 0, 0);

  u16* op = ao + (long)b*NTOK*DM + (long)h*64;
  #pragma unroll
  for (int mi = 0; mi < 4; ++mi)
    #pragma unroll
    for (int r = 0; r < 4; ++r) {
      const int tok = tok0 + mi*16 + g*4 + r;
      const float inv = 1.0f / rs[mi][r];
      #pragma unroll
      for (int ni = 0; ni < 4; ++ni)
        op[(long)tok*DM + ni*16 + c] = f2b(oacc[mi][ni][r] * inv);
    }
}

extern "C" void kernel_launch(void* const* d_in, const int* in_sizes, int n_in,
                              void* d_out, int out_size, void* d_ws, size_t ws_size,
                              hipStream_t stream) {
  const float* hs   = (const float*)d_in[0];
  const float* Wqkv = (const float*)d_in[1];
  const float* bqkv = (const float*)d_in[2];
  const float* Wout = (const float*)d_in[3];
  const float* bout = (const float*)d_in[4];
  float* out = (float*)d_out;
  char* w = (char*)d_ws;

  u16*  Xb    = (u16*)(w);                 // 32MB; dead after gemm0
  float* zp   = (float*)(w);               // aliases Xb (written by k_pa after gemm0), 8MB
  float* sp   = (float*)(w + 8388608L);
  u16*  WqkvT = (u16*)(w + 33554432L);
  u16*  WoutT = (u16*)(w + 39845888L);
  u16*  q     = (u16*)(w + 41943040L);
  float* psum = (float*)(w + 41943040L);   // aliases q: consumed by k_lreduce BEFORE gemm0 writes q
  u16*  k     = (u16*)(w + 75497472L);
  float* Xl   = (float*)(w + 109051904L);
  u16*  vt    = (u16*)(w + 142606336L);    // written directly by gemm0's V epilogue
  float* qlf  = (float*)(w + 176160768L);
  float* klf  = (float*)(w + 177209344L);
  u16*  qlb   = (u16*)(w + 178257920L);
  u16*  klb   = (u16*)(w + 178782208L);
  float* a2i  = (float*)(w + 179306496L);
  u16*  w2t   = (u16*)(w + 181403648L);
  u16*  ao    = (u16*)(w + 181927936L);

  k_pre<<<2048, 256, 0, stream>>>(hs, Xb, Xl, Wqkv, WqkvT, Wout, WoutT);
  k_lproj2<<<dim3(8,8,8), 256, 0, stream>>>(Xl, Wqkv, psum);
  k_lreduce<<<2048, 256, 0, stream>>>(psum, bqkv, qlf, klf, qlb, klb);
  k_gemm256<0><<<dim3(64,12), 512, 0, stream>>>(Xb, WqkvT, bqkv, 3072, nullptr, q, k, vt);
  k_pa<<<576, 512, 0, stream>>>(qlf, klf, a2i, qlb, k, vt, zp, sp);
  k_w2<<<64, 1024, 0, stream>>>(a2i, zp, sp, w2t);
  k_attn1<<<1024, 256, 0, stream>>>(q, klb, w2t, ao);
  k_gemm256<1><<<dim3(64,4), 512, 0, stream>>>(ao, WoutT, bout, 1024, out, nullptr, nullptr, nullptr);
}